// Round 5
// baseline (772.360 us; speedup 1.0000x reference)
//
#include <hip/hip_runtime.h>
#include <hip/hip_bf16.h>
#include <math.h>

#define BATCH 8
#define NPTS  1024
#define DIM   1024
#define HID   64
#define KNN   20
#define NMAT  16
#define KPACK 3072   // 3 bf16 segments stored contiguously per row: k = seg*1024 + d

typedef __attribute__((ext_vector_type(8))) short short8;
typedef __attribute__((ext_vector_type(4))) float floatx4;

__device__ __forceinline__ const float* mat_base(const float* f1, const float* f2, int m) {
    return (m < BATCH) ? (f1 + (size_t)m * NPTS * DIM)
                       : (f2 + (size_t)(m - BATCH) * NPTS * DIM);
}

__device__ __forceinline__ unsigned short f2bf_bits(float v) {
    __hip_bfloat16 h = __float2bfloat16(v);   // RNE
    return *(unsigned short*)&h;
}
__device__ __forceinline__ float bfbits2f(unsigned short b) {
    union { unsigned u; float f; } c; c.u = ((unsigned)b) << 16; return c.f;
}

// ---------------- K1: FUSED 3-way bf16 split + squared norms + y = f @ W1a ----------------
__global__ __launch_bounds__(256) void split_ymlp_kernel(const float* __restrict__ f1,
                                                         const float* __restrict__ f2,
                                                         const float* __restrict__ W,
                                                         unsigned short* __restrict__ H,
                                                         float* __restrict__ sq,
                                                         float* __restrict__ y) {
    int row0 = blockIdx.x * 64;                 // 64-row blocks never straddle matrices
    int m = row0 >> 10;
    const float* A = mat_base(f1, f2, m) + (size_t)(row0 & (NPTS - 1)) * DIM;
    unsigned short* Hb = H + (size_t)row0 * KPACK;
    __shared__ float As[64][20];
    __shared__ float Ws[16][HID];
    int tid = threadIdx.x;
    int r = tid >> 2, cq = (tid & 3) * 4;       // fixed load assignment: row r, cols cq..cq+3
    int ty = tid >> 4, tx = tid & 15;
    float acc[4][4];
    #pragma unroll
    for (int i = 0; i < 4; ++i)
        #pragma unroll
        for (int j = 0; j < 4; ++j) acc[i][j] = 0.f;
    float sqp = 0.f;
    unsigned short* Hr = Hb + (size_t)r * KPACK + cq;

    for (int kk = 0; kk < DIM; kk += 16) {
        float4 a = *(const float4*)&A[(size_t)r * DIM + kk + cq];
        // ---- split (bitwise-identical to old split_kernel chain) ----
        {
            float vv[4] = {a.x, a.y, a.z, a.w};
            unsigned short h1[4], h2[4], h3[4];
            #pragma unroll
            for (int c = 0; c < 4; ++c) {
                unsigned short b1 = f2bf_bits(vv[c]);
                float r1 = vv[c] - bfbits2f(b1);
                unsigned short b2 = f2bf_bits(r1);
                float r2 = r1 - bfbits2f(b2);
                unsigned short b3 = f2bf_bits(r2);
                h1[c] = b1; h2[c] = b2; h3[c] = b3;
            }
            *(ushort4*)&Hr[kk]        = *(ushort4*)&h1[0];
            *(ushort4*)&Hr[1024 + kk] = *(ushort4*)&h2[0];
            *(ushort4*)&Hr[2048 + kk] = *(ushort4*)&h3[0];
            sqp += a.x * a.x + a.y * a.y + a.z * a.z + a.w * a.w;
        }
        // ---- GEMM staging ----
        *(float4*)&As[r][cq] = a;
        {
            int d = tid >> 4, hh = (tid & 15) * 4;
            *(float4*)&Ws[d][hh] = *(const float4*)&W[(size_t)(kk + d) * HID + hh];
        }
        __syncthreads();
        #pragma unroll
        for (int k = 0; k < 16; ++k) {
            float av[4];
            #pragma unroll
            for (int ii = 0; ii < 4; ++ii) av[ii] = As[ty * 4 + ii][k];
            float4 w = *(const float4*)&Ws[k][tx * 4];
            #pragma unroll
            for (int ii = 0; ii < 4; ++ii) {
                acc[ii][0] += av[ii] * w.x;
                acc[ii][1] += av[ii] * w.y;
                acc[ii][2] += av[ii] * w.z;
                acc[ii][3] += av[ii] * w.w;
            }
        }
        __syncthreads();
    }
    sqp += __shfl_down(sqp, 1);
    sqp += __shfl_down(sqp, 2);
    if ((tid & 3) == 0) sq[row0 + r] = sqp;
    #pragma unroll
    for (int ii = 0; ii < 4; ++ii)
        *(float4*)&y[(size_t)(row0 + ty * 4 + ii) * HID + tx * 4] = *(float4*)&acc[ii][0];
}

// ---------------- K2: Gram -> squared distances via bf16 MFMA ----------------
// R5: self-syncing full-tiling for L2 residency. 512 blocks (2/CU, ONE dispatch round,
// all start together), full 8x8=64 tiles per matrix (no mirror stores); each block does
// 2 jobs: (matrix xcd, tile g) then (matrix xcd+8, tile g). All blocks march kk in
// near-lockstep -> per-slice per-XCD live set = current 32-k window only (<= ~3MB even
// under worst-case XCD mapping) -> staged re-reads hit L2 instead of streaming from LLC
// (the ~5 TB/s wall of R0-R3). L2 gives negative feedback on drift (laggards hit, leaders
// miss) -> self-synchronizing. Pipeline = R3 verbatim (triple-buffer, vmcnt(24), setprio).
// Lower-triangle tiles (bi>bj) issue the 6 split products in TRANSPOSED pair order
// (0,0),(0,1),(0,2),(1,0),(1,1),(2,0): per-term products and the accumulation chain are
// bitwise-identical to the old mirrored values (IEEE mul/add commute; MFMA k-reduction
// order is hardware-fixed), so dist/topk/output are unchanged.
#define GRAM_MFMA_SET(AF_S, BF)                                                            \
    _Pragma("unroll")                                                                      \
    for (int a = 0; a < 2; ++a)                                                            \
      _Pragma("unroll")                                                                    \
      for (int b = 0; b < 8; ++b)                                                          \
        acc[a][b] = __builtin_amdgcn_mfma_f32_16x16x32_bf16(AF_S[a], BF[b],                \
                                                            acc[a][b], 0, 0, 0);

#define GRAM_COMPUTE(CURAF, CBUF)                                                          \
    if (!lower) {                                                                          \
      _Pragma("unroll")                                                                    \
      for (int sb = 0; sb < 3; ++sb) {                                                     \
        short8 bf[8];                                                                      \
        _Pragma("unroll")                                                                  \
        for (int b = 0; b < 8; ++b)                                                        \
          bf[b] = *(const short8*)&Bsl[CBUF][(sb * 8 + b) * 512 + lane * 8];               \
        _Pragma("unroll")                                                                  \
        for (int sa = 0; sa < 3; ++sa) {                                                   \
          if (sa + sb > 2) continue;                                                       \
          GRAM_MFMA_SET(CURAF[sa], bf)                                                     \
        }                                                                                  \
      }                                                                                    \
    } else {                                                                               \
      short8 bfK[8], bfT[8];                                                               \
      _Pragma("unroll")                                                                    \
      for (int b = 0; b < 8; ++b)                                                          \
        bfK[b] = *(const short8*)&Bsl[CBUF][(0 * 8 + b) * 512 + lane * 8];                 \
      GRAM_MFMA_SET(CURAF[0], bfK)            /* (0,0) */                                  \
      _Pragma("unroll")                                                                    \
      for (int b = 0; b < 8; ++b)                                                          \
        bfT[b] = *(const short8*)&Bsl[CBUF][(1 * 8 + b) * 512 + lane * 8];                 \
      GRAM_MFMA_SET(CURAF[0], bfT)            /* (0,1) */                                  \
      _Pragma("unroll")                                                                    \
      for (int b = 0; b < 8; ++b)                                                          \
        bfT[b] = *(const short8*)&Bsl[CBUF][(2 * 8 + b) * 512 + lane * 8];                 \
      GRAM_MFMA_SET(CURAF[0], bfT)            /* (0,2) */                                  \
      GRAM_MFMA_SET(CURAF[1], bfK)            /* (1,0) */                                  \
      _Pragma("unroll")                                                                    \
      for (int b = 0; b < 8; ++b)                                                          \
        bfT[b] = *(const short8*)&Bsl[CBUF][(1 * 8 + b) * 512 + lane * 8];                 \
      GRAM_MFMA_SET(CURAF[1], bfT)            /* (1,1) */                                  \
      GRAM_MFMA_SET(CURAF[2], bfK)            /* (2,0) */                                  \
    }

#define GRAM_STEP(CURAF, NXTAF, CBUF, NBUF, KN, ISSUE, WAITOP)                             \
  {                                                                                        \
    if (ISSUE) {                                                                           \
      _Pragma("unroll")                                                                    \
      for (int s = 0; s < 3; ++s)                                                          \
        _Pragma("unroll")                                                                  \
        for (int a = 0; a < 2; ++a)                                                        \
          NXTAF[s][a] = *(const short8*)&Hm[(size_t)(ti + ((w << 1) + a) * 16 + r16) * KPACK \
                                            + (size_t)(s << 10) + (KN) + (kc << 3)];       \
      _Pragma("unroll")                                                                    \
      for (int c = 0; c < 6; ++c) {                                                        \
        int ca = w * 6 + c; int seg = ca >> 3; int rb = ca & 7;                            \
        const unsigned short* gb = Hm + (size_t)(tj + rb * 16 + r16) * KPACK               \
                                      + (size_t)(seg << 10) + (KN) + (kc << 3);            \
        __builtin_amdgcn_global_load_lds(                                                  \
            (const __attribute__((address_space(1))) void*)gb,                             \
            (__attribute__((address_space(3))) void*)&Bsl[NBUF][ca * 512], 16, 0, 0);      \
      }                                                                                    \
    }                                                                                      \
    asm volatile(WAITOP ::: "memory");                                                     \
    __builtin_amdgcn_s_barrier();                                                          \
    asm volatile("" ::: "memory");                                                         \
    __builtin_amdgcn_s_setprio(1);                                                         \
    GRAM_COMPUTE(CURAF, CBUF)                                                              \
    __builtin_amdgcn_s_setprio(0);                                                         \
    asm volatile("" ::: "memory");                                                         \
    __builtin_amdgcn_s_barrier();                                                          \
  }

__global__ __launch_bounds__(256, 2) void gram_mfma_kernel(const unsigned short* __restrict__ H,
                                                           const float* __restrict__ sq,
                                                           float* __restrict__ dist) {
    int bid = blockIdx.x;                 // 0..511 : one dispatch round, all co-start
    int xcd = bid & 7;
    int g = bid >> 3;                     // 0..63 : full 8x8 tile grid
    int bi = g >> 3, bj = g & 7;
    int ti = bi << 7, tj = bj << 7;
    bool lower = bi > bj;

    // B chunks: ca = seg*8 + colblk ; each chunk: [lane(64)][8 shorts] = 1KB (16 cols x 32 k)
    __shared__ __align__(16) unsigned short Bsl[3][24 * 512];   // 3 x 24 KB triple buffer

    int tid = threadIdx.x;
    int w = tid >> 6, lane = tid & 63;
    int r16 = lane & 15, kc = lane >> 4;

    #pragma unroll 1
    for (int job = 0; job < 2; ++job) {
        int m = xcd + 8 * job;            // this block's matrices: xcd, then xcd+8
        const unsigned short* Hm = H + (size_t)m * NPTS * KPACK;

        floatx4 acc[2][8];
        #pragma unroll
        for (int a = 0; a < 2; ++a)
            #pragma unroll
            for (int b = 0; b < 8; ++b) acc[a][b] = (floatx4)0.f;

        // A fragment triple buffers: wave-private rows ti + w*32 .. +31 (3 segs x 2 rowblocks)
        short8 afA[3][2], afB[3][2], afC[3][2];

        // ---- prologue: slice 0 -> afA/Bsl[0], slice 1 -> afB/Bsl[1]  (24 VMEM in flight) ----
        #pragma unroll
        for (int s = 0; s < 3; ++s)
            #pragma unroll
            for (int a = 0; a < 2; ++a) {
                size_t rowb = (size_t)(ti + ((w << 1) + a) * 16 + r16) * KPACK
                              + (size_t)(s << 10) + (kc << 3);
                afA[s][a] = *(const short8*)&Hm[rowb];
                afB[s][a] = *(const short8*)&Hm[rowb + 32];
            }
        #pragma unroll
        for (int c = 0; c < 6; ++c) {
            int ca = w * 6 + c; int seg = ca >> 3; int rb = ca & 7;
            const unsigned short* gb = Hm + (size_t)(tj + rb * 16 + r16) * KPACK
                                          + (size_t)(seg << 10) + (kc << 3);
            __builtin_amdgcn_global_load_lds(
                (const __attribute__((address_space(1))) void*)gb,
                (__attribute__((address_space(3))) void*)&Bsl[0][ca * 512], 16, 0, 0);
            __builtin_amdgcn_global_load_lds(
                (const __attribute__((address_space(1))) void*)(gb + 32),
                (__attribute__((address_space(3))) void*)&Bsl[1][ca * 512], 16, 0, 0);
        }

        // slices 0..29: compute t, issue t+2, wait vmcnt(24) (t+1,t+2 in flight)
        #pragma unroll 1
        for (int t2 = 0; t2 < 30; t2 += 3) {
            GRAM_STEP(afA, afC, 0, 2, (t2 + 2) * 32, 1, "s_waitcnt vmcnt(24)");
            GRAM_STEP(afB, afA, 1, 0, (t2 + 3) * 32, 1, "s_waitcnt vmcnt(24)");
            GRAM_STEP(afC, afB, 2, 1, (t2 + 4) * 32, 1, "s_waitcnt vmcnt(24)");
        }
        // epilogue: slice 30 (slice 31 still in flight), then slice 31
        GRAM_STEP(afA, afC, 0, 2, 0, 0, "s_waitcnt vmcnt(12)");
        GRAM_STEP(afB, afC, 1, 2, 0, 0, "s_waitcnt vmcnt(0)");

        const float* sqm = sq + m * NPTS;
        #pragma unroll
        for (int a = 0; a < 2; ++a) {
            int i0 = ti + ((w << 1) + a) * 16 + (lane >> 4) * 4;
            #pragma unroll
            for (int b = 0; b < 8; ++b) {
                int j = tj + b * 16 + (lane & 15);
                float sqj = sqm[j];
                #pragma unroll
                for (int r = 0; r < 4; ++r) {
                    int i = i0 + r;
                    float v = sqm[i] + sqj - 2.f * acc[a][b][r];
                    if (i == j) v += 1e10f;
                    dist[((size_t)m * NPTS + i) * NPTS + j] = v;   // own tile only, no mirror
                }
            }
        }
    }
}

// ---------------- K3: top-k (k=20 smallest), one wave per row, all-register ----------------
__global__ __launch_bounds__(256) void topk_kernel(const float* __restrict__ dist,
                                                   int* __restrict__ knn_idx) {
    int tid = threadIdx.x;
    int wave = tid >> 6, lane = tid & 63;
    int row = blockIdx.x * 4 + wave;
    const float* d = dist + (size_t)row * NPTS;
    float v[16];
    #pragma unroll
    for (int s = 0; s < 16; ++s) v[s] = d[s * 64 + lane];
    int myj = 0;
    for (int sel = 0; sel < KNN; ++sel) {
        float bv = v[0]; int bs = 0;
        #pragma unroll
        for (int s = 1; s < 16; ++s)
            if (v[s] < bv) { bv = v[s]; bs = s; }   // ascending s: lowest j locally on ties
        int bj = bs * 64 + lane;
        #pragma unroll
        for (int off = 1; off < 64; off <<= 1) {
            float ov = __shfl_xor(bv, off);
            int   oj = __shfl_xor(bj, off);
            if (ov < bv || (ov == bv && oj < bj)) { bv = ov; bj = oj; }
        }
        if ((bj & 63) == lane) v[bj >> 6] = 3e38f;  // owner clears
        if (lane == sel) myj = bj;
    }
    if (lane < KNN) knn_idx[(size_t)row * KNN + lane] = myj;
}

// ---------------- K5: t1 = relu(y_i + sum y_n + b1a); h1 = t1 @ W2a + b2a ----------------
__global__ __launch_bounds__(256) void t1h1_kernel(const float* __restrict__ y,
                                                   const int* __restrict__ knn_idx,
                                                   const float* __restrict__ W,
                                                   const float* __restrict__ bias1,
                                                   const float* __restrict__ bias2,
                                                   float* __restrict__ h1) {
    int row0 = blockIdx.x * 64;
    int m = row0 >> 10;
    __shared__ int nb[64 * KNN];
    __shared__ float t1s[64][65];
    __shared__ float Ws[64][HID];
    __shared__ float b1s[HID], b2s[HID];
    int tid = threadIdx.x;
    for (int k = tid; k < 64 * KNN; k += 256) nb[k] = knn_idx[(size_t)row0 * KNN + k];
    for (int k = tid; k < 64 * HID; k += 256) Ws[k >> 6][k & 63] = W[k];
    if (tid < HID) { b1s[tid] = bias1[tid]; b2s[tid] = bias2[tid]; }
    __syncthreads();
    {
        int r = tid >> 2, c0 = (tid & 3) * 16;
        const float* yr = y + (size_t)(row0 + r) * HID + c0;
        float4 a[4];
        #pragma unroll
        for (int q = 0; q < 4; ++q) a[q] = *(const float4*)&yr[q * 4];
        const float* ym = y + (size_t)(m << 10) * HID;
        #pragma unroll
        for (int t = 0; t < KNN; ++t) {
            const float* yn = ym + (size_t)nb[r * KNN + t] * HID + c0;
            #pragma unroll
            for (int q = 0; q < 4; ++q) {
                float4 v = *(const float4*)&yn[q * 4];
                a[q].x += v.x; a[q].y += v.y; a[q].z += v.z; a[q].w += v.w;
            }
        }
        #pragma unroll
        for (int q = 0; q < 4; ++q) {
            int c = c0 + q * 4;
            t1s[r][c + 0] = fmaxf(a[q].x + b1s[c + 0], 0.f);
            t1s[r][c + 1] = fmaxf(a[q].y + b1s[c + 1], 0.f);
            t1s[r][c + 2] = fmaxf(a[q].z + b1s[c + 2], 0.f);
            t1s[r][c + 3] = fmaxf(a[q].w + b1s[c + 3], 0.f);
        }
    }
    __syncthreads();
    int ty = tid >> 4, tx = tid & 15;
    float acc[4][4];
    #pragma unroll
    for (int i = 0; i < 4; ++i)
        #pragma unroll
        for (int j = 0; j < 4; ++j) acc[i][j] = 0.f;
    #pragma unroll
    for (int k = 0; k < HID; ++k) {
        float a[4];
        #pragma unroll
        for (int ii = 0; ii < 4; ++ii) a[ii] = t1s[ty * 4 + ii][k];
        float4 w = *(const float4*)&Ws[k][tx * 4];
        #pragma unroll
        for (int ii = 0; ii < 4; ++ii) {
            acc[ii][0] += a[ii] * w.x;
            acc[ii][1] += a[ii] * w.y;
            acc[ii][2] += a[ii] * w.z;
            acc[ii][3] += a[ii] * w.w;
        }
    }
    #pragma unroll
    for (int ii = 0; ii < 4; ++ii) {
        float o[4];
        #pragma unroll
        for (int jj = 0; jj < 4; ++jj) o[jj] = acc[ii][jj] + b2s[tx * 4 + jj];
        *(float4*)&h1[(size_t)(row0 + ty * 4 + ii) * HID + tx * 4] = *(float4*)&o[0];
    }
}

// ---------------- K6: hs = h1_i + sum h1_n; t2 = relu(hs@W1b+b1b); z = t2@W2b+b2b ----------------
__global__ __launch_bounds__(256) void t2z_kernel(const float* __restrict__ h1,
                                                  const int* __restrict__ knn_idx,
                                                  const float* __restrict__ W1,
                                                  const float* __restrict__ bias1,
                                                  const float* __restrict__ W2,
                                                  const float* __restrict__ bias2,
                                                  float* __restrict__ z) {
    int row0 = blockIdx.x * 64;
    int m = row0 >> 10;
    __shared__ int nb[64 * KNN];
    __shared__ float hs[64][65];
    __shared__ float t2s[64][65];
    __shared__ float Ws[64][HID];
    __shared__ float b1s[HID], b2s[HID];
    int tid = threadIdx.x;
    for (int k = tid; k < 64 * KNN; k += 256) nb[k] = knn_idx[(size_t)row0 * KNN + k];
    for (int k = tid; k < 64 * HID; k += 256) Ws[k >> 6][k & 63] = W1[k];
    if (tid < HID) { b1s[tid] = bias1[tid]; b2s[tid] = bias2[tid]; }
    __syncthreads();
    {
        int r = tid >> 2, c0 = (tid & 3) * 16;
        const float* hr = h1 + (size_t)(row0 + r) * HID + c0;
        float4 a[4];
        #pragma unroll
        for (int q = 0; q < 4; ++q) a[q] = *(const float4*)&hr[q * 4];
        const float* hm = h1 + (size_t)(m << 10) * HID;
        #pragma unroll
        for (int t = 0; t < KNN; ++t) {
            const float* hn = hm + (size_t)nb[r * KNN + t] * HID + c0;
            #pragma unroll
            for (int q = 0; q < 4; ++q) {
                float4 v = *(const float4*)&hn[q * 4];
                a[q].x += v.x; a[q].y += v.y; a[q].z += v.z; a[q].w += v.w;
            }
        }
        #pragma unroll
        for (int q = 0; q < 4; ++q) *(float4*)&hs[r][c0 + q * 4] = a[q];
    }
    __syncthreads();
    int ty = tid >> 4, tx = tid & 15;
    float acc[4][4];
    #pragma unroll
    for (int i = 0; i < 4; ++i)
        #pragma unroll
        for (int j = 0; j < 4; ++j) acc[i][j] = 0.f;
    #pragma unroll
    for (int k = 0; k < HID; ++k) {
        float a[4];
        #pragma unroll
        for (int ii = 0; ii < 4; ++ii) a[ii] = hs[ty * 4 + ii][k];
        float4 w = *(const float4*)&Ws[k][tx * 4];
        #pragma unroll
        for (int ii = 0; ii < 4; ++ii) {
            acc[ii][0] += a[ii] * w.x;
            acc[ii][1] += a[ii] * w.y;
            acc[ii][2] += a[ii] * w.z;
            acc[ii][3] += a[ii] * w.w;
        }
    }
    #pragma unroll
    for (int ii = 0; ii < 4; ++ii)
        #pragma unroll
        for (int jj = 0; jj < 4; ++jj)
            t2s[ty * 4 + ii][tx * 4 + jj] = fmaxf(acc[ii][jj] + b1s[tx * 4 + jj], 0.f);
    __syncthreads();
    for (int k = tid; k < 64 * HID; k += 256) Ws[k >> 6][k & 63] = W2[k];
    __syncthreads();
    #pragma unroll
    for (int i = 0; i < 4; ++i)
        #pragma unroll
        for (int j = 0; j < 4; ++j) acc[i][j] = 0.f;
    #pragma unroll
    for (int k = 0; k < HID; ++k) {
        float a[4];
        #pragma unroll
        for (int ii = 0; ii < 4; ++ii) a[ii] = t2s[ty * 4 + ii][k];
        float4 w = *(const float4*)&Ws[k][tx * 4];
        #pragma unroll
        for (int ii = 0; ii < 4; ++ii) {
            acc[ii][0] += a[ii] * w.x;
            acc[ii][1] += a[ii] * w.y;
            acc[ii][2] += a[ii] * w.z;
            acc[ii][3] += a[ii] * w.w;
        }
    }
    #pragma unroll
    for (int ii = 0; ii < 4; ++ii) {
        float o[4];
        #pragma unroll
        for (int jj = 0; jj < 4; ++jj) o[jj] = acc[ii][jj] + b2s[tx * 4 + jj];
        *(float4*)&z[(size_t)(row0 + ty * 4 + ii) * HID + tx * 4] = *(float4*)&o[0];
    }
}

// ---------------- K7: sim = z1 @ z2^T (64x64 tiles, K=64) ----------------
__global__ __launch_bounds__(256) void sim_kernel(const float* __restrict__ z,
                                                  float* __restrict__ logits) {
    int bid = blockIdx.x;
    int b = bid >> 8;
    int tile = bid & 255;
    int ti = (tile >> 4) << 6;
    int tj = (tile & 15) << 6;
    const float* z1 = z + (size_t)b * NPTS * HID;
    const float* z2 = z + (size_t)(BATCH + b) * NPTS * HID;
    __shared__ float Z1[64][68];
    __shared__ float Z2[64][68];
    int tid = threadIdx.x;
    #pragma unroll
    for (int i = 0; i < 4; ++i) {
        int l = tid + i * 256;
        int r = l >> 4, c = (l & 15) * 4;
        *(float4*)&Z1[r][c] = *(const float4*)&z1[(size_t)(ti + r) * HID + c];
        *(float4*)&Z2[r][c] = *(const float4*)&z2[(size_t)(tj + r) * HID + c];
    }
    __syncthreads();
    int ty = tid >> 4, tx = tid & 15;
    float acc[4][4];
    #pragma unroll
    for (int i = 0; i < 4; ++i)
        #pragma unroll
        for (int j = 0; j < 4; ++j) acc[i][j] = 0.f;
    #pragma unroll
    for (int h = 0; h < HID; ++h) {
        float a[4], bb[4];
        #pragma unroll
        for (int ii = 0; ii < 4; ++ii) { a[ii] = Z1[ty * 4 + ii][h]; bb[ii] = Z2[tx * 4 + ii][h]; }
        #pragma unroll
        for (int ii = 0; ii < 4; ++ii)
            #pragma unroll
            for (int jj = 0; jj < 4; ++jj)
                acc[ii][jj] += a[ii] * bb[jj];
    }
    #pragma unroll
    for (int ii = 0; ii < 4; ++ii) {
        float* dst = logits + ((size_t)b * NPTS + ti + ty * 4 + ii) * NPTS + tj + tx * 4;
        *(float4*)&dst[0] = *(float4*)&acc[ii][0];
    }
}

// ---------------- K8: row softmax ----------------
__global__ __launch_bounds__(256) void softmax_kernel(const float* __restrict__ logits,
                                                      float* __restrict__ out) {
    int row = blockIdx.x;                         // 0..8191
    const float* L = logits + (size_t)row * NPTS;
    __shared__ float buf[NPTS];
    __shared__ float red[8];
    int tid = threadIdx.x;
    int wave = tid >> 6, lane = tid & 63;
    float mx = -3e38f;
    #pragma unroll
    for (int s = 0; s < 4; ++s) {
        float v = L[tid + s * 256];
        buf[tid + s * 256] = v;
        mx = fmaxf(mx, v);
    }
    #pragma unroll
    for (int off = 32; off > 0; off >>= 1) mx = fmaxf(mx, __shfl_down(mx, off));
    if (lane == 0) red[wave] = mx;
    __syncthreads();
    mx = fmaxf(fmaxf(red[0], red[1]), fmaxf(red[2], red[3]));
    float sum = 0.f;
    #pragma unroll
    for (int s = 0; s < 4; ++s) {
        float e = expf(buf[tid + s * 256] - mx);
        buf[tid + s * 256] = e;
        sum += e;
    }
    #pragma unroll
    for (int off = 32; off > 0; off >>= 1) sum += __shfl_down(sum, off);
    if (lane == 0) red[4 + wave] = sum;
    __syncthreads();
    float inv = 1.f / (red[4] + red[5] + red[6] + red[7]);
    #pragma unroll
    for (int s = 0; s < 4; ++s)
        out[(size_t)row * NPTS + tid + s * 256] = buf[tid + s * 256] * inv;
}

extern "C" void kernel_launch(void* const* d_in, const int* in_sizes, int n_in,
                              void* d_out, int out_size, void* d_ws, size_t ws_size,
                              hipStream_t stream) {
    const float* f1  = (const float*)d_in[0];
    const float* f2  = (const float*)d_in[1];
    const float* W1a = (const float*)d_in[2];
    const float* b1a = (const float*)d_in[3];
    const float* W2a = (const float*)d_in[4];
    const float* b2a = (const float*)d_in[5];
    const float* W1b = (const float*)d_in[6];
    const float* b1b = (const float*)d_in[7];
    const float* W2b = (const float*)d_in[8];
    const float* b2b = (const float*)d_in[9];
    float* out = (float*)d_out;

    // workspace: H packed (100.7MB) | dist (67.1MB, reused as sim logits) | sq | kidx | y | h1 | z
    char* ws = (char*)d_ws;
    unsigned short* H = (unsigned short*)ws;
    float* dist = (float*)(ws + (size_t)NMAT * NPTS * KPACK * sizeof(unsigned short));
    float* sq   = dist + (size_t)NMAT * NPTS * NPTS;
    int*   kidx = (int*)(sq + NMAT * NPTS);
    float* ybuf = (float*)(kidx + NMAT * NPTS * KNN);
    float* h1b  = ybuf + (size_t)NMAT * NPTS * HID;
    float* zb   = h1b + (size_t)NMAT * NPTS * HID;

    split_ymlp_kernel<<<NMAT * NPTS / 64, 256, 0, stream>>>(f1, f2, W1a, H, sq, ybuf);
    gram_mfma_kernel<<<512, 256, 0, stream>>>(H, sq, dist);   // 2/CU, single dispatch round
    topk_kernel<<<NMAT * NPTS / 4, 256, 0, stream>>>(dist, kidx);
    t1h1_kernel<<<NMAT * NPTS / 64, 256, 0, stream>>>(ybuf, kidx, W2a, b1a, b2a, h1b);
    t2z_kernel<<<NMAT * NPTS / 64, 256, 0, stream>>>(h1b, kidx, W1b, b1b, W2b, b2b, zb);
    sim_kernel<<<BATCH * 256, 256, 0, stream>>>(zb, dist);                      // dist := logits
    softmax_kernel<<<BATCH * NPTS, 256, 0, stream>>>(dist, out);
}

// Round 7
// 565.634 us; speedup vs baseline: 1.3655x; 1.3655x over previous
//
#include <hip/hip_runtime.h>
#include <hip/hip_bf16.h>
#include <math.h>

#define BATCH 8
#define NPTS  1024
#define DIM   1024
#define HID   64
#define KNN   20
#define NMAT  16
#define KPACK 3072   // 3 bf16 segments stored contiguously per row: k = seg*1024 + d

typedef __attribute__((ext_vector_type(8))) short short8;
typedef __attribute__((ext_vector_type(4))) float floatx4;

__device__ __forceinline__ const float* mat_base(const float* f1, const float* f2, int m) {
    return (m < BATCH) ? (f1 + (size_t)m * NPTS * DIM)
                       : (f2 + (size_t)(m - BATCH) * NPTS * DIM);
}

__device__ __forceinline__ unsigned short f2bf_bits(float v) {
    __hip_bfloat16 h = __float2bfloat16(v);   // RNE
    return *(unsigned short*)&h;
}
__device__ __forceinline__ float bfbits2f(unsigned short b) {
    union { unsigned u; float f; } c; c.u = ((unsigned)b) << 16; return c.f;
}

// ---------------- K1: FUSED 3-way bf16 split + squared norms + y = f @ W1a ----------------
__global__ __launch_bounds__(256) void split_ymlp_kernel(const float* __restrict__ f1,
                                                         const float* __restrict__ f2,
                                                         const float* __restrict__ W,
                                                         unsigned short* __restrict__ H,
                                                         float* __restrict__ sq,
                                                         float* __restrict__ y) {
    int row0 = blockIdx.x * 64;                 // 64-row blocks never straddle matrices
    int m = row0 >> 10;
    const float* A = mat_base(f1, f2, m) + (size_t)(row0 & (NPTS - 1)) * DIM;
    unsigned short* Hb = H + (size_t)row0 * KPACK;
    __shared__ float As[64][20];
    __shared__ float Ws[16][HID];
    int tid = threadIdx.x;
    int r = tid >> 2, cq = (tid & 3) * 4;       // fixed load assignment: row r, cols cq..cq+3
    int ty = tid >> 4, tx = tid & 15;
    float acc[4][4];
    #pragma unroll
    for (int i = 0; i < 4; ++i)
        #pragma unroll
        for (int j = 0; j < 4; ++j) acc[i][j] = 0.f;
    float sqp = 0.f;
    unsigned short* Hr = Hb + (size_t)r * KPACK + cq;

    for (int kk = 0; kk < DIM; kk += 16) {
        float4 a = *(const float4*)&A[(size_t)r * DIM + kk + cq];
        // ---- split (bitwise-identical to old split_kernel chain) ----
        {
            float vv[4] = {a.x, a.y, a.z, a.w};
            unsigned short h1[4], h2[4], h3[4];
            #pragma unroll
            for (int c = 0; c < 4; ++c) {
                unsigned short b1 = f2bf_bits(vv[c]);
                float r1 = vv[c] - bfbits2f(b1);
                unsigned short b2 = f2bf_bits(r1);
                float r2 = r1 - bfbits2f(b2);
                unsigned short b3 = f2bf_bits(r2);
                h1[c] = b1; h2[c] = b2; h3[c] = b3;
            }
            *(ushort4*)&Hr[kk]        = *(ushort4*)&h1[0];
            *(ushort4*)&Hr[1024 + kk] = *(ushort4*)&h2[0];
            *(ushort4*)&Hr[2048 + kk] = *(ushort4*)&h3[0];
            sqp += a.x * a.x + a.y * a.y + a.z * a.z + a.w * a.w;
        }
        // ---- GEMM staging ----
        *(float4*)&As[r][cq] = a;
        {
            int d = tid >> 4, hh = (tid & 15) * 4;
            *(float4*)&Ws[d][hh] = *(const float4*)&W[(size_t)(kk + d) * HID + hh];
        }
        __syncthreads();
        #pragma unroll
        for (int k = 0; k < 16; ++k) {
            float av[4];
            #pragma unroll
            for (int ii = 0; ii < 4; ++ii) av[ii] = As[ty * 4 + ii][k];
            float4 w = *(const float4*)&Ws[k][tx * 4];
            #pragma unroll
            for (int ii = 0; ii < 4; ++ii) {
                acc[ii][0] += av[ii] * w.x;
                acc[ii][1] += av[ii] * w.y;
                acc[ii][2] += av[ii] * w.z;
                acc[ii][3] += av[ii] * w.w;
            }
        }
        __syncthreads();
    }
    sqp += __shfl_down(sqp, 1);
    sqp += __shfl_down(sqp, 2);
    if ((tid & 3) == 0) sq[row0 + r] = sqp;
    #pragma unroll
    for (int ii = 0; ii < 4; ++ii)
        *(float4*)&y[(size_t)(row0 + ty * 4 + ii) * HID + tx * 4] = *(float4*)&acc[ii][0];
}

// ---------------- K2: Gram -> squared distances via bf16 MFMA ----------------
// R7: EXACT R3 revert (proven 183.7us, passed): 2-slice-deep pipeline, triple-buffered B
// in LDS (3x24KB=72KB, 2 blocks/CU via launch_bounds(256,2)), triple-buffered A frags in
// regs, steady-state vmcnt(24), setprio around MFMA cluster. The R6 bounds-3 experiment
// (flaky + slow) is reverted; do NOT change launch_bounds without re-verifying (rule #18
// class miscompile risk around inline-asm waits).
#define GRAM_STEP(CURAF, NXTAF, CBUF, NBUF, KN, ISSUE, WAITOP)                             \
  {                                                                                        \
    if (ISSUE) {                                                                           \
      _Pragma("unroll")                                                                    \
      for (int s = 0; s < 3; ++s)                                                          \
        _Pragma("unroll")                                                                  \
        for (int a = 0; a < 2; ++a)                                                        \
          NXTAF[s][a] = *(const short8*)&Hm[(size_t)(ti + ((w << 1) + a) * 16 + r16) * KPACK \
                                            + (size_t)(s << 10) + (KN) + (kc << 3)];       \
      _Pragma("unroll")                                                                    \
      for (int c = 0; c < 6; ++c) {                                                        \
        int ca = w * 6 + c; int seg = ca >> 3; int rb = ca & 7;                            \
        const unsigned short* gb = Hm + (size_t)(tj + rb * 16 + r16) * KPACK               \
                                      + (size_t)(seg << 10) + (KN) + (kc << 3);            \
        __builtin_amdgcn_global_load_lds(                                                  \
            (const __attribute__((address_space(1))) void*)gb,                             \
            (__attribute__((address_space(3))) void*)&Bsl[NBUF][ca * 512], 16, 0, 0);      \
      }                                                                                    \
    }                                                                                      \
    asm volatile(WAITOP ::: "memory");                                                     \
    __builtin_amdgcn_s_barrier();                                                          \
    asm volatile("" ::: "memory");                                                         \
    __builtin_amdgcn_s_setprio(1);                                                         \
    _Pragma("unroll")                                                                      \
    for (int sb = 0; sb < 3; ++sb) {                                                       \
      short8 bf[8];                                                                        \
      _Pragma("unroll")                                                                    \
      for (int b = 0; b < 8; ++b)                                                          \
        bf[b] = *(const short8*)&Bsl[CBUF][(sb * 8 + b) * 512 + lane * 8];                 \
      _Pragma("unroll")                                                                    \
      for (int sa = 0; sa < 3; ++sa) {                                                     \
        if (sa + sb > 2) continue;                                                         \
        _Pragma("unroll")                                                                  \
        for (int a = 0; a < 2; ++a)                                                        \
          _Pragma("unroll")                                                                \
          for (int b = 0; b < 8; ++b)                                                      \
            acc[a][b] = __builtin_amdgcn_mfma_f32_16x16x32_bf16(CURAF[sa][a], bf[b],       \
                                                                acc[a][b], 0, 0, 0);       \
      }                                                                                    \
    }                                                                                      \
    __builtin_amdgcn_s_setprio(0);                                                         \
    asm volatile("" ::: "memory");                                                         \
    __builtin_amdgcn_s_barrier();                                                          \
  }

__global__ __launch_bounds__(256, 2) void gram_mfma_kernel(const unsigned short* __restrict__ H,
                                                           const float* __restrict__ sq,
                                                           float* __restrict__ dist) {
    int bid = blockIdx.x;
    int xcd = bid & 7;
    int g = bid >> 3;                 // 0..71
    int m = xcd + 8 * (g & 1);        // interleave this XCD's two matrices
    int t = g >> 1;                   // 0..35
    int bi = 0;
    { int a = t; while (a >= 8 - bi) { a -= 8 - bi; ++bi; } t = a; }
    int bj = bi + t;
    int ti = bi << 7, tj = bj << 7;

    const unsigned short* Hm = H + (size_t)m * NPTS * KPACK;

    // B chunks: ca = seg*8 + colblk ; each chunk: [lane(64)][8 shorts] = 1KB (16 cols x 32 k)
    __shared__ __align__(16) unsigned short Bsl[3][24 * 512];   // 3 x 24 KB triple buffer

    int tid = threadIdx.x;
    int w = tid >> 6, lane = tid & 63;
    int r16 = lane & 15, kc = lane >> 4;

    floatx4 acc[2][8];
    #pragma unroll
    for (int a = 0; a < 2; ++a)
        #pragma unroll
        for (int b = 0; b < 8; ++b) acc[a][b] = (floatx4)0.f;

    // A fragment triple buffers: wave-disjoint rows ti + w*32 .. +31 (3 segs x 2 rowblocks)
    short8 afA[3][2], afB[3][2], afC[3][2];

    // ---- prologue: slice 0 -> afA/Bsl[0], slice 1 -> afB/Bsl[1]  (24 VMEM in flight) ----
    #pragma unroll
    for (int s = 0; s < 3; ++s)
        #pragma unroll
        for (int a = 0; a < 2; ++a) {
            size_t rowb = (size_t)(ti + ((w << 1) + a) * 16 + r16) * KPACK + (size_t)(s << 10) + (kc << 3);
            afA[s][a] = *(const short8*)&Hm[rowb];
            afB[s][a] = *(const short8*)&Hm[rowb + 32];
        }
    #pragma unroll
    for (int c = 0; c < 6; ++c) {
        int ca = w * 6 + c; int seg = ca >> 3; int rb = ca & 7;
        const unsigned short* gb = Hm + (size_t)(tj + rb * 16 + r16) * KPACK
                                      + (size_t)(seg << 10) + (kc << 3);
        __builtin_amdgcn_global_load_lds(
            (const __attribute__((address_space(1))) void*)gb,
            (__attribute__((address_space(3))) void*)&Bsl[0][ca * 512], 16, 0, 0);
        __builtin_amdgcn_global_load_lds(
            (const __attribute__((address_space(1))) void*)(gb + 32),
            (__attribute__((address_space(3))) void*)&Bsl[1][ca * 512], 16, 0, 0);
    }

    // slices 0..29: compute t, issue t+2, wait vmcnt(24) (t+1,t+2 in flight)
    #pragma unroll 1
    for (int t2 = 0; t2 < 30; t2 += 3) {
        GRAM_STEP(afA, afC, 0, 2, (t2 + 2) * 32, 1, "s_waitcnt vmcnt(24)");
        GRAM_STEP(afB, afA, 1, 0, (t2 + 3) * 32, 1, "s_waitcnt vmcnt(24)");
        GRAM_STEP(afC, afB, 2, 1, (t2 + 4) * 32, 1, "s_waitcnt vmcnt(24)");
    }
    // epilogue: slice 30 (slice 31 still in flight), then slice 31
    GRAM_STEP(afA, afC, 0, 2, 0, 0, "s_waitcnt vmcnt(12)");
    GRAM_STEP(afB, afC, 1, 2, 0, 0, "s_waitcnt vmcnt(0)");

    const float* sqm = sq + m * NPTS;
    #pragma unroll
    for (int a = 0; a < 2; ++a) {
        int i0 = ti + ((w << 1) + a) * 16 + (lane >> 4) * 4;
        #pragma unroll
        for (int b = 0; b < 8; ++b) {
            int j = tj + b * 16 + (lane & 15);
            float sqj = sqm[j];
            #pragma unroll
            for (int r = 0; r < 4; ++r) {
                int i = i0 + r;
                float v = sqm[i] + sqj - 2.f * acc[a][b][r];
                if (i == j) v += 1e10f;
                dist[((size_t)m * NPTS + i) * NPTS + j] = v;
                if (bi != bj) dist[((size_t)m * NPTS + j) * NPTS + i] = v;
            }
        }
    }
}

// ---------------- K3: top-k (k=20 smallest), one wave per row, all-register ----------------
__global__ __launch_bounds__(256) void topk_kernel(const float* __restrict__ dist,
                                                   int* __restrict__ knn_idx) {
    int tid = threadIdx.x;
    int wave = tid >> 6, lane = tid & 63;
    int row = blockIdx.x * 4 + wave;
    const float* d = dist + (size_t)row * NPTS;
    float v[16];
    #pragma unroll
    for (int s = 0; s < 16; ++s) v[s] = d[s * 64 + lane];
    int myj = 0;
    for (int sel = 0; sel < KNN; ++sel) {
        float bv = v[0]; int bs = 0;
        #pragma unroll
        for (int s = 1; s < 16; ++s)
            if (v[s] < bv) { bv = v[s]; bs = s; }   // ascending s: lowest j locally on ties
        int bj = bs * 64 + lane;
        #pragma unroll
        for (int off = 1; off < 64; off <<= 1) {
            float ov = __shfl_xor(bv, off);
            int   oj = __shfl_xor(bj, off);
            if (ov < bv || (ov == bv && oj < bj)) { bv = ov; bj = oj; }
        }
        if ((bj & 63) == lane) v[bj >> 6] = 3e38f;  // owner clears
        if (lane == sel) myj = bj;
    }
    if (lane < KNN) knn_idx[(size_t)row * KNN + lane] = myj;
}

// ---------------- K5: t1 = relu(y_i + sum y_n + b1a); h1 = t1 @ W2a + b2a ----------------
__global__ __launch_bounds__(256) void t1h1_kernel(const float* __restrict__ y,
                                                   const int* __restrict__ knn_idx,
                                                   const float* __restrict__ W,
                                                   const float* __restrict__ bias1,
                                                   const float* __restrict__ bias2,
                                                   float* __restrict__ h1) {
    int row0 = blockIdx.x * 64;
    int m = row0 >> 10;
    __shared__ int nb[64 * KNN];
    __shared__ float t1s[64][65];
    __shared__ float Ws[64][HID];
    __shared__ float b1s[HID], b2s[HID];
    int tid = threadIdx.x;
    for (int k = tid; k < 64 * KNN; k += 256) nb[k] = knn_idx[(size_t)row0 * KNN + k];
    for (int k = tid; k < 64 * HID; k += 256) Ws[k >> 6][k & 63] = W[k];
    if (tid < HID) { b1s[tid] = bias1[tid]; b2s[tid] = bias2[tid]; }
    __syncthreads();
    {
        int r = tid >> 2, c0 = (tid & 3) * 16;
        const float* yr = y + (size_t)(row0 + r) * HID + c0;
        float4 a[4];
        #pragma unroll
        for (int q = 0; q < 4; ++q) a[q] = *(const float4*)&yr[q * 4];
        const float* ym = y + (size_t)(m << 10) * HID;
        #pragma unroll
        for (int t = 0; t < KNN; ++t) {
            const float* yn = ym + (size_t)nb[r * KNN + t] * HID + c0;
            #pragma unroll
            for (int q = 0; q < 4; ++q) {
                float4 v = *(const float4*)&yn[q * 4];
                a[q].x += v.x; a[q].y += v.y; a[q].z += v.z; a[q].w += v.w;
            }
        }
        #pragma unroll
        for (int q = 0; q < 4; ++q) {
            int c = c0 + q * 4;
            t1s[r][c + 0] = fmaxf(a[q].x + b1s[c + 0], 0.f);
            t1s[r][c + 1] = fmaxf(a[q].y + b1s[c + 1], 0.f);
            t1s[r][c + 2] = fmaxf(a[q].z + b1s[c + 2], 0.f);
            t1s[r][c + 3] = fmaxf(a[q].w + b1s[c + 3], 0.f);
        }
    }
    __syncthreads();
    int ty = tid >> 4, tx = tid & 15;
    float acc[4][4];
    #pragma unroll
    for (int i = 0; i < 4; ++i)
        #pragma unroll
        for (int j = 0; j < 4; ++j) acc[i][j] = 0.f;
    #pragma unroll
    for (int k = 0; k < HID; ++k) {
        float a[4];
        #pragma unroll
        for (int ii = 0; ii < 4; ++ii) a[ii] = t1s[ty * 4 + ii][k];
        float4 w = *(const float4*)&Ws[k][tx * 4];
        #pragma unroll
        for (int ii = 0; ii < 4; ++ii) {
            acc[ii][0] += a[ii] * w.x;
            acc[ii][1] += a[ii] * w.y;
            acc[ii][2] += a[ii] * w.z;
            acc[ii][3] += a[ii] * w.w;
        }
    }
    #pragma unroll
    for (int ii = 0; ii < 4; ++ii) {
        float o[4];
        #pragma unroll
        for (int jj = 0; jj < 4; ++jj) o[jj] = acc[ii][jj] + b2s[tx * 4 + jj];
        *(float4*)&h1[(size_t)(row0 + ty * 4 + ii) * HID + tx * 4] = *(float4*)&o[0];
    }
}

// ---------------- K6: hs = h1_i + sum h1_n; t2 = relu(hs@W1b+b1b); z = t2@W2b+b2b ----------------
__global__ __launch_bounds__(256) void t2z_kernel(const float* __restrict__ h1,
                                                  const int* __restrict__ knn_idx,
                                                  const float* __restrict__ W1,
                                                  const float* __restrict__ bias1,
                                                  const float* __restrict__ W2,
                                                  const float* __restrict__ bias2,
                                                  float* __restrict__ z) {
    int row0 = blockIdx.x * 64;
    int m = row0 >> 10;
    __shared__ int nb[64 * KNN];
    __shared__ float hs[64][65];
    __shared__ float t2s[64][65];
    __shared__ float Ws[64][HID];
    __shared__ float b1s[HID], b2s[HID];
    int tid = threadIdx.x;
    for (int k = tid; k < 64 * KNN; k += 256) nb[k] = knn_idx[(size_t)row0 * KNN + k];
    for (int k = tid; k < 64 * HID; k += 256) Ws[k >> 6][k & 63] = W1[k];
    if (tid < HID) { b1s[tid] = bias1[tid]; b2s[tid] = bias2[tid]; }
    __syncthreads();
    {
        int r = tid >> 2, c0 = (tid & 3) * 16;
        const float* hr = h1 + (size_t)(row0 + r) * HID + c0;
        float4 a[4];
        #pragma unroll
        for (int q = 0; q < 4; ++q) a[q] = *(const float4*)&hr[q * 4];
        const float* hm = h1 + (size_t)(m << 10) * HID;
        #pragma unroll
        for (int t = 0; t < KNN; ++t) {
            const float* hn = hm + (size_t)nb[r * KNN + t] * HID + c0;
            #pragma unroll
            for (int q = 0; q < 4; ++q) {
                float4 v = *(const float4*)&hn[q * 4];
                a[q].x += v.x; a[q].y += v.y; a[q].z += v.z; a[q].w += v.w;
            }
        }
        #pragma unroll
        for (int q = 0; q < 4; ++q) *(float4*)&hs[r][c0 + q * 4] = a[q];
    }
    __syncthreads();
    int ty = tid >> 4, tx = tid & 15;
    float acc[4][4];
    #pragma unroll
    for (int i = 0; i < 4; ++i)
        #pragma unroll
        for (int j = 0; j < 4; ++j) acc[i][j] = 0.f;
    #pragma unroll
    for (int k = 0; k < HID; ++k) {
        float a[4];
        #pragma unroll
        for (int ii = 0; ii < 4; ++ii) a[ii] = hs[ty * 4 + ii][k];
        float4 w = *(const float4*)&Ws[k][tx * 4];
        #pragma unroll
        for (int ii = 0; ii < 4; ++ii) {
            acc[ii][0] += a[ii] * w.x;
            acc[ii][1] += a[ii] * w.y;
            acc[ii][2] += a[ii] * w.z;
            acc[ii][3] += a[ii] * w.w;
        }
    }
    #pragma unroll
    for (int ii = 0; ii < 4; ++ii)
        #pragma unroll
        for (int jj = 0; jj < 4; ++jj)
            t2s[ty * 4 + ii][tx * 4 + jj] = fmaxf(acc[ii][jj] + b1s[tx * 4 + jj], 0.f);
    __syncthreads();
    for (int k = tid; k < 64 * HID; k += 256) Ws[k >> 6][k & 63] = W2[k];
    __syncthreads();
    #pragma unroll
    for (int i = 0; i < 4; ++i)
        #pragma unroll
        for (int j = 0; j < 4; ++j) acc[i][j] = 0.f;
    #pragma unroll
    for (int k = 0; k < HID; ++k) {
        float a[4];
        #pragma unroll
        for (int ii = 0; ii < 4; ++ii) a[ii] = t2s[ty * 4 + ii][k];
        float4 w = *(const float4*)&Ws[k][tx * 4];
        #pragma unroll
        for (int ii = 0; ii < 4; ++ii) {
            acc[ii][0] += a[ii] * w.x;
            acc[ii][1] += a[ii] * w.y;
            acc[ii][2] += a[ii] * w.z;
            acc[ii][3] += a[ii] * w.w;
        }
    }
    #pragma unroll
    for (int ii = 0; ii < 4; ++ii) {
        float o[4];
        #pragma unroll
        for (int jj = 0; jj < 4; ++jj) o[jj] = acc[ii][jj] + b2s[tx * 4 + jj];
        *(float4*)&z[(size_t)(row0 + ty * 4 + ii) * HID + tx * 4] = *(float4*)&o[0];
    }
}

// ---------------- K7: FUSED sim + softmax ----------------
// Per block: 32 rows of one batch. S[32][1024] = z1_rows @ z2^T in LDS with the SAME
// per-element fp32 fma chain (ascending h) as the old sim_kernel -> logits bitwise-
// identical; then row softmax in-place (reductions reassociated ~1e-7 << tolerance).
// Saves the 67MB logits round-trip + one launch. LDS 153KB -> 1 block/CU.
__global__ __launch_bounds__(256) void simsoftmax_kernel(const float* __restrict__ z,
                                                         float* __restrict__ out) {
    int bid = blockIdx.x;             // 0..255
    int b = bid >> 5;                 // batch
    int r0 = (bid & 31) * 32;         // row block
    const float* z1 = z + (size_t)b * NPTS * HID + (size_t)r0 * HID;
    const float* z2 = z + (size_t)(BATCH + b) * NPTS * HID;
    __shared__ float S[32][1024];     // 128 KB
    __shared__ float Z2[64][68];      // 17 KB
    __shared__ float Z1[32][64];      // 8 KB
    int tid = threadIdx.x;
    {
        int r = tid >> 3, c = (tid & 7) * 8;
        *(float4*)&Z1[r][c]     = *(const float4*)&z1[(size_t)r * HID + c];
        *(float4*)&Z1[r][c + 4] = *(const float4*)&z1[(size_t)r * HID + c + 4];
    }
    int ty = tid >> 4, tx = tid & 15;
    for (int jt = 0; jt < 16; ++jt) {
        __syncthreads();
        {
            int r = tid >> 2, c = (tid & 3) * 16;
            const float* zr = z2 + (size_t)(jt * 64 + r) * HID + c;
            *(float4*)&Z2[r][c]      = *(const float4*)&zr[0];
            *(float4*)&Z2[r][c + 4]  = *(const float4*)&zr[4];
            *(float4*)&Z2[r][c + 8]  = *(const float4*)&zr[8];
            *(float4*)&Z2[r][c + 12] = *(const float4*)&zr[12];
        }
        __syncthreads();
        float acc[2][4];
        #pragma unroll
        for (int i = 0; i < 2; ++i)
            #pragma unroll
            for (int j = 0; j < 4; ++j) acc[i][j] = 0.f;
        #pragma unroll
        for (int h = 0; h < HID; ++h) {
            float a[2], bb[4];
            #pragma unroll
            for (int i = 0; i < 2; ++i) a[i] = Z1[ty * 2 + i][h];
            #pragma unroll
            for (int j = 0; j < 4; ++j) bb[j] = Z2[tx * 4 + j][h];
            #pragma unroll
            for (int i = 0; i < 2; ++i)
                #pragma unroll
                for (int j = 0; j < 4; ++j)
                    acc[i][j] += a[i] * bb[j];
        }
        #pragma unroll
        for (int i = 0; i < 2; ++i)
            *(float4*)&S[ty * 2 + i][jt * 64 + tx * 4] = *(float4*)&acc[i][0];
    }
    __syncthreads();
    // softmax: 4 waves x 8 rows each
    int wv = tid >> 6, lane = tid & 63;
    #pragma unroll 1
    for (int rr = 0; rr < 8; ++rr) {
        int r = wv * 8 + rr;
        float mx = -3e38f;
        #pragma unroll
        for (int s = 0; s < 16; ++s) mx = fmaxf(mx, S[r][lane + s * 64]);
        #pragma unroll
        for (int off = 32; off > 0; off >>= 1) mx = fmaxf(mx, __shfl_xor(mx, off));
        float sum = 0.f;
        #pragma unroll
        for (int s = 0; s < 16; ++s) {
            float e = expf(S[r][lane + s * 64] - mx);
            S[r][lane + s * 64] = e;
            sum += e;
        }
        #pragma unroll
        for (int off = 32; off > 0; off >>= 1) sum += __shfl_xor(sum, off);
        float inv = 1.f / sum;
        float* orow = out + ((size_t)b * NPTS + r0 + r) * NPTS;
        #pragma unroll
        for (int s = 0; s < 16; ++s)
            orow[lane + s * 64] = S[r][lane + s * 64] * inv;
    }
}

extern "C" void kernel_launch(void* const* d_in, const int* in_sizes, int n_in,
                              void* d_out, int out_size, void* d_ws, size_t ws_size,
                              hipStream_t stream) {
    const float* f1  = (const float*)d_in[0];
    const float* f2  = (const float*)d_in[1];
    const float* W1a = (const float*)d_in[2];
    const float* b1a = (const float*)d_in[3];
    const float* W2a = (const float*)d_in[4];
    const float* b2a = (const float*)d_in[5];
    const float* W1b = (const float*)d_in[6];
    const float* b1b = (const float*)d_in[7];
    const float* W2b = (const float*)d_in[8];
    const float* b2b = (const float*)d_in[9];
    float* out = (float*)d_out;

    // workspace: H packed (100.7MB) | dist (67.1MB) | sq | kidx | y | h1 | z
    char* ws = (char*)d_ws;
    unsigned short* H = (unsigned short*)ws;
    float* dist = (float*)(ws + (size_t)NMAT * NPTS * KPACK * sizeof(unsigned short));
    float* sq   = dist + (size_t)NMAT * NPTS * NPTS;
    int*   kidx = (int*)(sq + NMAT * NPTS);
    float* ybuf = (float*)(kidx + NMAT * NPTS * KNN);
    float* h1b  = ybuf + (size_t)NMAT * NPTS * HID;
    float* zb   = h1b + (size_t)NMAT * NPTS * HID;

    split_ymlp_kernel<<<NMAT * NPTS / 64, 256, 0, stream>>>(f1, f2, W1a, H, sq, ybuf);
    gram_mfma_kernel<<<NMAT * 36, 256, 0, stream>>>(H, sq, dist);
    topk_kernel<<<NMAT * NPTS / 4, 256, 0, stream>>>(dist, kidx);
    t1h1_kernel<<<NMAT * NPTS / 64, 256, 0, stream>>>(ybuf, kidx, W2a, b1a, b2a, h1b);
    t2z_kernel<<<NMAT * NPTS / 64, 256, 0, stream>>>(h1b, kidx, W1b, b1b, W2b, b2b, zb);
    simsoftmax_kernel<<<BATCH * 32, 256, 0, stream>>>(zb, out);
}

// Round 9
// 530.870 us; speedup vs baseline: 1.4549x; 1.0655x over previous
//
#include <hip/hip_runtime.h>
#include <hip/hip_bf16.h>
#include <math.h>

#define BATCH 8
#define NPTS  1024
#define DIM   1024
#define HID   64
#define KNN   20
#define NMAT  16
#define KPACK 3072   // 3 bf16 segments stored contiguously per row: k = seg*1024 + d

typedef __attribute__((ext_vector_type(8))) short short8;
typedef __attribute__((ext_vector_type(4))) float floatx4;

__device__ __forceinline__ const float* mat_base(const float* f1, const float* f2, int m) {
    return (m < BATCH) ? (f1 + (size_t)m * NPTS * DIM)
                       : (f2 + (size_t)(m - BATCH) * NPTS * DIM);
}

__device__ __forceinline__ unsigned short f2bf_bits(float v) {
    __hip_bfloat16 h = __float2bfloat16(v);   // RNE
    return *(unsigned short*)&h;
}
__device__ __forceinline__ float bfbits2f(unsigned short b) {
    union { unsigned u; float f; } c; c.u = ((unsigned)b) << 16; return c.f;
}

// ---------------- K1: FUSED 3-way bf16 split + squared norms + y = f @ W1a ----------------
__global__ __launch_bounds__(256) void split_ymlp_kernel(const float* __restrict__ f1,
                                                         const float* __restrict__ f2,
                                                         const float* __restrict__ W,
                                                         unsigned short* __restrict__ H,
                                                         float* __restrict__ sq,
                                                         float* __restrict__ y) {
    int row0 = blockIdx.x * 64;                 // 64-row blocks never straddle matrices
    int m = row0 >> 10;
    const float* A = mat_base(f1, f2, m) + (size_t)(row0 & (NPTS - 1)) * DIM;
    unsigned short* Hb = H + (size_t)row0 * KPACK;
    __shared__ float As[64][20];
    __shared__ float Ws[16][HID];
    int tid = threadIdx.x;
    int r = tid >> 2, cq = (tid & 3) * 4;       // fixed load assignment: row r, cols cq..cq+3
    int ty = tid >> 4, tx = tid & 15;
    float acc[4][4];
    #pragma unroll
    for (int i = 0; i < 4; ++i)
        #pragma unroll
        for (int j = 0; j < 4; ++j) acc[i][j] = 0.f;
    float sqp = 0.f;
    unsigned short* Hr = Hb + (size_t)r * KPACK + cq;

    for (int kk = 0; kk < DIM; kk += 16) {
        float4 a = *(const float4*)&A[(size_t)r * DIM + kk + cq];
        // ---- split (bitwise-identical to old split_kernel chain) ----
        {
            float vv[4] = {a.x, a.y, a.z, a.w};
            unsigned short h1[4], h2[4], h3[4];
            #pragma unroll
            for (int c = 0; c < 4; ++c) {
                unsigned short b1 = f2bf_bits(vv[c]);
                float r1 = vv[c] - bfbits2f(b1);
                unsigned short b2 = f2bf_bits(r1);
                float r2 = r1 - bfbits2f(b2);
                unsigned short b3 = f2bf_bits(r2);
                h1[c] = b1; h2[c] = b2; h3[c] = b3;
            }
            *(ushort4*)&Hr[kk]        = *(ushort4*)&h1[0];
            *(ushort4*)&Hr[1024 + kk] = *(ushort4*)&h2[0];
            *(ushort4*)&Hr[2048 + kk] = *(ushort4*)&h3[0];
            sqp += a.x * a.x + a.y * a.y + a.z * a.z + a.w * a.w;
        }
        // ---- GEMM staging ----
        *(float4*)&As[r][cq] = a;
        {
            int d = tid >> 4, hh = (tid & 15) * 4;
            *(float4*)&Ws[d][hh] = *(const float4*)&W[(size_t)(kk + d) * HID + hh];
        }
        __syncthreads();
        #pragma unroll
        for (int k = 0; k < 16; ++k) {
            float av[4];
            #pragma unroll
            for (int ii = 0; ii < 4; ++ii) av[ii] = As[ty * 4 + ii][k];
            float4 w = *(const float4*)&Ws[k][tx * 4];
            #pragma unroll
            for (int ii = 0; ii < 4; ++ii) {
                acc[ii][0] += av[ii] * w.x;
                acc[ii][1] += av[ii] * w.y;
                acc[ii][2] += av[ii] * w.z;
                acc[ii][3] += av[ii] * w.w;
            }
        }
        __syncthreads();
    }
    sqp += __shfl_down(sqp, 1);
    sqp += __shfl_down(sqp, 2);
    if ((tid & 3) == 0) sq[row0 + r] = sqp;
    #pragma unroll
    for (int ii = 0; ii < 4; ++ii)
        *(float4*)&y[(size_t)(row0 + ty * 4 + ii) * HID + tx * 4] = *(float4*)&acc[ii][0];
}

// ---------------- K2: Gram -> squared distances via bf16 MFMA ----------------
// R9 = R8 retile + PROLOGUE DRAIN FIX. R8's bug: prologue issue order (afA/afB
// interleaved, then B0/B1 DMAs interleaved) didn't match the vmcnt(18) drain
// granularity -> slice 0 computed from un-arrived afA[2][1] and Bsl[0]. Fix:
// grouped prologue (afA | B0-DMA | afB | B1-DMA, pinned by compiler barriers)
// + a single s_waitcnt vmcnt(0) after the prologue. Steps 0/1 then wait on
// already-drained data (vmcnt(18) is a no-op at 9/18 outstanding); steady state
// t>=2 retires exactly slice t's 9 loads (6 A-reg + 3 B-DMA, issued A-then-DMA
// per slice). Each wave drains its OWN DMAs before the shared barrier ->
// cross-wave LDS visibility via barrier. (Also fixes R3/R7's latent slice-0
// prologue race - they relied on timing.)
// Tiling: 128x64, 72 tiles/matrix (bi 0..7 x bjj>=2bi), 1152 blocks -> kills the
// R7 occupancy tail (2 rounds -> 2.25 rounds of half-size blocks = 1.125T).
// Coverage verified: direct region floor(c/64)>=2*floor(r/128); straddle tiles
// (bjj>>1==bi) cover the diagonal band directly; non-straddle mirror. Disjoint+
// exhaustive. Per-element accumulation chain unchanged -> dist bitwise == R3.
#define GRAM_STEP(CURAF, NXTAF, CBUF, NBUF, KN, ISSUE, WAITOP)                             \
  {                                                                                        \
    if (ISSUE) {                                                                           \
      _Pragma("unroll")                                                                    \
      for (int s = 0; s < 3; ++s)                                                          \
        _Pragma("unroll")                                                                  \
        for (int a = 0; a < 2; ++a)                                                        \
          NXTAF[s][a] = *(const short8*)&Hm[(size_t)(ti + ((w << 1) + a) * 16 + r16) * KPACK \
                                            + (size_t)(s << 10) + (KN) + (kc << 3)];       \
      _Pragma("unroll")                                                                    \
      for (int c = 0; c < 3; ++c) {                                                        \
        int ca = w * 3 + c; int seg = ca >> 2; int cb = ca & 3;                            \
        const unsigned short* gb = Hm + (size_t)(tj + cb * 16 + r16) * KPACK               \
                                      + (size_t)(seg << 10) + (KN) + (kc << 3);            \
        __builtin_amdgcn_global_load_lds(                                                  \
            (const __attribute__((address_space(1))) void*)gb,                             \
            (__attribute__((address_space(3))) void*)&Bsl[NBUF][ca * 512], 16, 0, 0);      \
      }                                                                                    \
    }                                                                                      \
    asm volatile(WAITOP ::: "memory");                                                     \
    __builtin_amdgcn_s_barrier();                                                          \
    asm volatile("" ::: "memory");                                                         \
    __builtin_amdgcn_s_setprio(1);                                                         \
    _Pragma("unroll")                                                                      \
    for (int sb = 0; sb < 3; ++sb) {                                                       \
      short8 bf[4];                                                                        \
      _Pragma("unroll")                                                                    \
      for (int b = 0; b < 4; ++b)                                                          \
        bf[b] = *(const short8*)&Bsl[CBUF][(sb * 4 + b) * 512 + lane * 8];                 \
      _Pragma("unroll")                                                                    \
      for (int sa = 0; sa < 3; ++sa) {                                                     \
        if (sa + sb > 2) continue;                                                         \
        _Pragma("unroll")                                                                  \
        for (int a = 0; a < 2; ++a)                                                        \
          _Pragma("unroll")                                                                \
          for (int b = 0; b < 4; ++b)                                                      \
            acc[a][b] = __builtin_amdgcn_mfma_f32_16x16x32_bf16(CURAF[sa][a], bf[b],       \
                                                                acc[a][b], 0, 0, 0);       \
      }                                                                                    \
    }                                                                                      \
    __builtin_amdgcn_s_setprio(0);                                                         \
    asm volatile("" ::: "memory");                                                         \
    __builtin_amdgcn_s_barrier();                                                          \
  }

__global__ __launch_bounds__(256, 2) void gram_mfma_kernel(const unsigned short* __restrict__ H,
                                                           const float* __restrict__ sq,
                                                           float* __restrict__ dist) {
    int bid = blockIdx.x;
    int xcd = bid & 7;
    int g = bid >> 3;                 // 0..143
    int m = xcd + 8 * (g & 1);        // interleave this XCD's two matrices
    int t = g >> 1;                   // 0..71 : tiles (bi, bjj) with bjj >= 2*bi
    int bi = 0;
    { int a = t; while (a >= 16 - 2 * bi) { a -= 16 - 2 * bi; ++bi; } t = a; }
    int bjj = 2 * bi + t;
    int ti = bi << 7, tj = bjj << 6;
    bool straddle = (bjj >> 1) == bi;  // tile overlaps the 128-wide diagonal band

    const unsigned short* Hm = H + (size_t)m * NPTS * KPACK;

    // B chunks: ca = seg*4 + colblk ; each chunk: [lane(64)][8 shorts] = 1KB (16 cols x 32 k)
    __shared__ __align__(16) unsigned short Bsl[3][12 * 512];   // 3 x 12 KB triple buffer

    int tid = threadIdx.x;
    int w = tid >> 6, lane = tid & 63;
    int r16 = lane & 15, kc = lane >> 4;

    floatx4 acc[2][4];
    #pragma unroll
    for (int a = 0; a < 2; ++a)
        #pragma unroll
        for (int b = 0; b < 4; ++b) acc[a][b] = (floatx4)0.f;

    // A fragment triple buffers: wave-disjoint rows ti + w*32 .. +31 (3 segs x 2 rowblocks)
    short8 afA[3][2], afB[3][2], afC[3][2];

    // ---- prologue (grouped: afA | B0-DMA | afB | B1-DMA, then full drain) ----
    #pragma unroll
    for (int s = 0; s < 3; ++s)
        #pragma unroll
        for (int a = 0; a < 2; ++a)
            afA[s][a] = *(const short8*)&Hm[(size_t)(ti + ((w << 1) + a) * 16 + r16) * KPACK
                                            + (size_t)(s << 10) + (kc << 3)];
    asm volatile("" ::: "memory");
    #pragma unroll
    for (int c = 0; c < 3; ++c) {
        int ca = w * 3 + c; int seg = ca >> 2; int cb = ca & 3;
        const unsigned short* gb = Hm + (size_t)(tj + cb * 16 + r16) * KPACK
                                      + (size_t)(seg << 10) + (kc << 3);
        __builtin_amdgcn_global_load_lds(
            (const __attribute__((address_space(1))) void*)gb,
            (__attribute__((address_space(3))) void*)&Bsl[0][ca * 512], 16, 0, 0);
    }
    asm volatile("" ::: "memory");
    #pragma unroll
    for (int s = 0; s < 3; ++s)
        #pragma unroll
        for (int a = 0; a < 2; ++a)
            afB[s][a] = *(const short8*)&Hm[(size_t)(ti + ((w << 1) + a) * 16 + r16) * KPACK
                                            + (size_t)(s << 10) + 32 + (kc << 3)];
    asm volatile("" ::: "memory");
    #pragma unroll
    for (int c = 0; c < 3; ++c) {
        int ca = w * 3 + c; int seg = ca >> 2; int cb = ca & 3;
        const unsigned short* gb = Hm + (size_t)(tj + cb * 16 + r16) * KPACK
                                      + (size_t)(seg << 10) + 32 + (kc << 3);
        __builtin_amdgcn_global_load_lds(
            (const __attribute__((address_space(1))) void*)gb,
            (__attribute__((address_space(3))) void*)&Bsl[1][ca * 512], 16, 0, 0);
    }
    // Full drain: slices 0 and 1 are complete before the loop. Steps 0/1's
    // vmcnt(18) become no-ops (9/18 outstanding); steady state from step 2.
    asm volatile("s_waitcnt vmcnt(0)" ::: "memory");

    // slices 0..29: compute t, issue t+2, wait vmcnt(18) (t+1,t+2 in flight: 9+9)
    #pragma unroll 1
    for (int t2 = 0; t2 < 30; t2 += 3) {
        GRAM_STEP(afA, afC, 0, 2, (t2 + 2) * 32, 1, "s_waitcnt vmcnt(18)");
        GRAM_STEP(afB, afA, 1, 0, (t2 + 3) * 32, 1, "s_waitcnt vmcnt(18)");
        GRAM_STEP(afC, afB, 2, 1, (t2 + 4) * 32, 1, "s_waitcnt vmcnt(18)");
    }
    // epilogue: slice 30 (slice 31 still in flight), then slice 31
    GRAM_STEP(afA, afC, 0, 2, 0, 0, "s_waitcnt vmcnt(9)");
    GRAM_STEP(afB, afC, 1, 2, 0, 0, "s_waitcnt vmcnt(0)");

    const float* sqm = sq + m * NPTS;
    #pragma unroll
    for (int a = 0; a < 2; ++a) {
        int i0 = ti + ((w << 1) + a) * 16 + (lane >> 4) * 4;
        #pragma unroll
        for (int b = 0; b < 4; ++b) {
            int j = tj + b * 16 + (lane & 15);
            float sqj = sqm[j];
            #pragma unroll
            for (int r = 0; r < 4; ++r) {
                int i = i0 + r;
                float v = sqm[i] + sqj - 2.f * acc[a][b][r];
                if (i == j) v += 1e10f;
                dist[((size_t)m * NPTS + i) * NPTS + j] = v;
                if (!straddle) dist[((size_t)m * NPTS + j) * NPTS + i] = v;
            }
        }
    }
}

// ---------------- K3: top-k (k=20 smallest), one wave per row, all-register ----------------
__global__ __launch_bounds__(256) void topk_kernel(const float* __restrict__ dist,
                                                   int* __restrict__ knn_idx) {
    int tid = threadIdx.x;
    int wave = tid >> 6, lane = tid & 63;
    int row = blockIdx.x * 4 + wave;
    const float* d = dist + (size_t)row * NPTS;
    float v[16];
    #pragma unroll
    for (int s = 0; s < 16; ++s) v[s] = d[s * 64 + lane];
    int myj = 0;
    for (int sel = 0; sel < KNN; ++sel) {
        float bv = v[0]; int bs = 0;
        #pragma unroll
        for (int s = 1; s < 16; ++s)
            if (v[s] < bv) { bv = v[s]; bs = s; }   // ascending s: lowest j locally on ties
        int bj = bs * 64 + lane;
        #pragma unroll
        for (int off = 1; off < 64; off <<= 1) {
            float ov = __shfl_xor(bv, off);
            int   oj = __shfl_xor(bj, off);
            if (ov < bv || (ov == bv && oj < bj)) { bv = ov; bj = oj; }
        }
        if ((bj & 63) == lane) v[bj >> 6] = 3e38f;  // owner clears
        if (lane == sel) myj = bj;
    }
    if (lane < KNN) knn_idx[(size_t)row * KNN + lane] = myj;
}

// ---------------- K5: t1 = relu(y_i + sum y_n + b1a); h1 = t1 @ W2a + b2a ----------------
__global__ __launch_bounds__(256) void t1h1_kernel(const float* __restrict__ y,
                                                   const int* __restrict__ knn_idx,
                                                   const float* __restrict__ W,
                                                   const float* __restrict__ bias1,
                                                   const float* __restrict__ bias2,
                                                   float* __restrict__ h1) {
    int row0 = blockIdx.x * 64;
    int m = row0 >> 10;
    __shared__ int nb[64 * KNN];
    __shared__ float t1s[64][65];
    __shared__ float Ws[64][HID];
    __shared__ float b1s[HID], b2s[HID];
    int tid = threadIdx.x;
    for (int k = tid; k < 64 * KNN; k += 256) nb[k] = knn_idx[(size_t)row0 * KNN + k];
    for (int k = tid; k < 64 * HID; k += 256) Ws[k >> 6][k & 63] = W[k];
    if (tid < HID) { b1s[tid] = bias1[tid]; b2s[tid] = bias2[tid]; }
    __syncthreads();
    {
        int r = tid >> 2, c0 = (tid & 3) * 16;
        const float* yr = y + (size_t)(row0 + r) * HID + c0;
        float4 a[4];
        #pragma unroll
        for (int q = 0; q < 4; ++q) a[q] = *(const float4*)&yr[q * 4];
        const float* ym = y + (size_t)(m << 10) * HID;
        #pragma unroll
        for (int t = 0; t < KNN; ++t) {
            const float* yn = ym + (size_t)nb[r * KNN + t] * HID + c0;
            #pragma unroll
            for (int q = 0; q < 4; ++q) {
                float4 v = *(const float4*)&yn[q * 4];
                a[q].x += v.x; a[q].y += v.y; a[q].z += v.z; a[q].w += v.w;
            }
        }
        #pragma unroll
        for (int q = 0; q < 4; ++q) {
            int c = c0 + q * 4;
            t1s[r][c + 0] = fmaxf(a[q].x + b1s[c + 0], 0.f);
            t1s[r][c + 1] = fmaxf(a[q].y + b1s[c + 1], 0.f);
            t1s[r][c + 2] = fmaxf(a[q].z + b1s[c + 2], 0.f);
            t1s[r][c + 3] = fmaxf(a[q].w + b1s[c + 3], 0.f);
        }
    }
    __syncthreads();
    int ty = tid >> 4, tx = tid & 15;
    float acc[4][4];
    #pragma unroll
    for (int i = 0; i < 4; ++i)
        #pragma unroll
        for (int j = 0; j < 4; ++j) acc[i][j] = 0.f;
    #pragma unroll
    for (int k = 0; k < HID; ++k) {
        float a[4];
        #pragma unroll
        for (int ii = 0; ii < 4; ++ii) a[ii] = t1s[ty * 4 + ii][k];
        float4 w = *(const float4*)&Ws[k][tx * 4];
        #pragma unroll
        for (int ii = 0; ii < 4; ++ii) {
            acc[ii][0] += a[ii] * w.x;
            acc[ii][1] += a[ii] * w.y;
            acc[ii][2] += a[ii] * w.z;
            acc[ii][3] += a[ii] * w.w;
        }
    }
    #pragma unroll
    for (int ii = 0; ii < 4; ++ii) {
        float o[4];
        #pragma unroll
        for (int jj = 0; jj < 4; ++jj) o[jj] = acc[ii][jj] + b2s[tx * 4 + jj];
        *(float4*)&h1[(size_t)(row0 + ty * 4 + ii) * HID + tx * 4] = *(float4*)&o[0];
    }
}

// ---------------- K6: hs = h1_i + sum h1_n; t2 = relu(hs@W1b+b1b); z = t2@W2b+b2b ----------------
__global__ __launch_bounds__(256) void t2z_kernel(const float* __restrict__ h1,
                                                  const int* __restrict__ knn_idx,
                                                  const float* __restrict__ W1,
                                                  const float* __restrict__ bias1,
                                                  const float* __restrict__ W2,
                                                  const float* __restrict__ bias2,
                                                  float* __restrict__ z) {
    int row0 = blockIdx.x * 64;
    int m = row0 >> 10;
    __shared__ int nb[64 * KNN];
    __shared__ float hs[64][65];
    __shared__ float t2s[64][65];
    __shared__ float Ws[64][HID];
    __shared__ float b1s[HID], b2s[HID];
    int tid = threadIdx.x;
    for (int k = tid; k < 64 * KNN; k += 256) nb[k] = knn_idx[(size_t)row0 * KNN + k];
    for (int k = tid; k < 64 * HID; k += 256) Ws[k >> 6][k & 63] = W1[k];
    if (tid < HID) { b1s[tid] = bias1[tid]; b2s[tid] = bias2[tid]; }
    __syncthreads();
    {
        int r = tid >> 2, c0 = (tid & 3) * 16;
        const float* hr = h1 + (size_t)(row0 + r) * HID + c0;
        float4 a[4];
        #pragma unroll
        for (int q = 0; q < 4; ++q) a[q] = *(const float4*)&hr[q * 4];
        const float* hm = h1 + (size_t)(m << 10) * HID;
        #pragma unroll
        for (int t = 0; t < KNN; ++t) {
            const float* hn = hm + (size_t)nb[r * KNN + t] * HID + c0;
            #pragma unroll
            for (int q = 0; q < 4; ++q) {
                float4 v = *(const float4*)&hn[q * 4];
                a[q].x += v.x; a[q].y += v.y; a[q].z += v.z; a[q].w += v.w;
            }
        }
        #pragma unroll
        for (int q = 0; q < 4; ++q) *(float4*)&hs[r][c0 + q * 4] = a[q];
    }
    __syncthreads();
    int ty = tid >> 4, tx = tid & 15;
    float acc[4][4];
    #pragma unroll
    for (int i = 0; i < 4; ++i)
        #pragma unroll
        for (int j = 0; j < 4; ++j) acc[i][j] = 0.f;
    #pragma unroll
    for (int k = 0; k < HID; ++k) {
        float a[4];
        #pragma unroll
        for (int ii = 0; ii < 4; ++ii) a[ii] = hs[ty * 4 + ii][k];
        float4 w = *(const float4*)&Ws[k][tx * 4];
        #pragma unroll
        for (int ii = 0; ii < 4; ++ii) {
            acc[ii][0] += a[ii] * w.x;
            acc[ii][1] += a[ii] * w.y;
            acc[ii][2] += a[ii] * w.z;
            acc[ii][3] += a[ii] * w.w;
        }
    }
    #pragma unroll
    for (int ii = 0; ii < 4; ++ii)
        #pragma unroll
        for (int jj = 0; jj < 4; ++jj)
            t2s[ty * 4 + ii][tx * 4 + jj] = fmaxf(acc[ii][jj] + b1s[tx * 4 + jj], 0.f);
    __syncthreads();
    for (int k = tid; k < 64 * HID; k += 256) Ws[k >> 6][k & 63] = W2[k];
    __syncthreads();
    #pragma unroll
    for (int i = 0; i < 4; ++i)
        #pragma unroll
        for (int j = 0; j < 4; ++j) acc[i][j] = 0.f;
    #pragma unroll
    for (int k = 0; k < HID; ++k) {
        float a[4];
        #pragma unroll
        for (int ii = 0; ii < 4; ++ii) a[ii] = t2s[ty * 4 + ii][k];
        float4 w = *(const float4*)&Ws[k][tx * 4];
        #pragma unroll
        for (int ii = 0; ii < 4; ++ii) {
            acc[ii][0] += a[ii] * w.x;
            acc[ii][1] += a[ii] * w.y;
            acc[ii][2] += a[ii] * w.z;
            acc[ii][3] += a[ii] * w.w;
        }
    }
    #pragma unroll
    for (int ii = 0; ii < 4; ++ii) {
        float o[4];
        #pragma unroll
        for (int jj = 0; jj < 4; ++jj) o[jj] = acc[ii][jj] + b2s[tx * 4 + jj];
        *(float4*)&z[(size_t)(row0 + ty * 4 + ii) * HID + tx * 4] = *(float4*)&o[0];
    }
}

// ---------------- K7: sim = z1 @ z2^T (64x64 tiles, K=64) ----------------
__global__ __launch_bounds__(256) void sim_kernel(const float* __restrict__ z,
                                                  float* __restrict__ logits) {
    int bid = blockIdx.x;
    int b = bid >> 8;
    int tile = bid & 255;
    int ti = (tile >> 4) << 6;
    int tj = (tile & 15) << 6;
    const float* z1 = z + (size_t)b * NPTS * HID;
    const float* z2 = z + (size_t)(BATCH + b) * NPTS * HID;
    __shared__ float Z1[64][68];
    __shared__ float Z2[64][68];
    int tid = threadIdx.x;
    #pragma unroll
    for (int i = 0; i < 4; ++i) {
        int l = tid + i * 256;
        int r = l >> 4, c = (l & 15) * 4;
        *(float4*)&Z1[r][c] = *(const float4*)&z1[(size_t)(ti + r) * HID + c];
        *(float4*)&Z2[r][c] = *(const float4*)&z2[(size_t)(tj + r) * HID + c];
    }
    __syncthreads();
    int ty = tid >> 4, tx = tid & 15;
    float acc[4][4];
    #pragma unroll
    for (int i = 0; i < 4; ++i)
        #pragma unroll
        for (int j = 0; j < 4; ++j) acc[i][j] = 0.f;
    #pragma unroll
    for (int h = 0; h < HID; ++h) {
        float a[4], bb[4];
        #pragma unroll
        for (int ii = 0; ii < 4; ++ii) { a[ii] = Z1[ty * 4 + ii][h]; bb[ii] = Z2[tx * 4 + ii][h]; }
        #pragma unroll
        for (int ii = 0; ii < 4; ++ii)
            #pragma unroll
            for (int jj = 0; jj < 4; ++jj)
                acc[ii][jj] += a[ii] * bb[jj];
    }
    #pragma unroll
    for (int ii = 0; ii < 4; ++ii) {
        float* dst = logits + ((size_t)b * NPTS + ti + ty * 4 + ii) * NPTS + tj + tx * 4;
        *(float4*)&dst[0] = *(float4*)&acc[ii][0];
    }
}

// ---------------- K8: row softmax ----------------
__global__ __launch_bounds__(256) void softmax_kernel(const float* __restrict__ logits,
                                                      float* __restrict__ out) {
    int row = blockIdx.x;                         // 0..8191
    const float* L = logits + (size_t)row * NPTS;
    __shared__ float buf[NPTS];
    __shared__ float red[8];
    int tid = threadIdx.x;
    int wave = tid >> 6, lane = tid & 63;
    float mx = -3e38f;
    #pragma unroll
    for (int s = 0; s < 4; ++s) {
        float v = L[tid + s * 256];
        buf[tid + s * 256] = v;
        mx = fmaxf(mx, v);
    }
    #pragma unroll
    for (int off = 32; off > 0; off >>= 1) mx = fmaxf(mx, __shfl_down(mx, off));
    if (lane == 0) red[wave] = mx;
    __syncthreads();
    mx = fmaxf(fmaxf(red[0], red[1]), fmaxf(red[2], red[3]));
    float sum = 0.f;
    #pragma unroll
    for (int s = 0; s < 4; ++s) {
        float e = expf(buf[tid + s * 256] - mx);
        buf[tid + s * 256] = e;
        sum += e;
    }
    #pragma unroll
    for (int off = 32; off > 0; off >>= 1) sum += __shfl_down(sum, off);
    if (lane == 0) red[4 + wave] = sum;
    __syncthreads();
    float inv = 1.f / (red[4] + red[5] + red[6] + red[7]);
    #pragma unroll
    for (int s = 0; s < 4; ++s)
        out[(size_t)row * NPTS + tid + s * 256] = buf[tid + s * 256] * inv;
}

extern "C" void kernel_launch(void* const* d_in, const int* in_sizes, int n_in,
                              void* d_out, int out_size, void* d_ws, size_t ws_size,
                              hipStream_t stream) {
    const float* f1  = (const float*)d_in[0];
    const float* f2  = (const float*)d_in[1];
    const float* W1a = (const float*)d_in[2];
    const float* b1a = (const float*)d_in[3];
    const float* W2a = (const float*)d_in[4];
    const float* b2a = (const float*)d_in[5];
    const float* W1b = (const float*)d_in[6];
    const float* b1b = (const float*)d_in[7];
    const float* W2b = (const float*)d_in[8];
    const float* b2b = (const float*)d_in[9];
    float* out = (float*)d_out;

    // workspace: H packed (100.7MB) | dist (67.1MB, reused as sim logits) | sq | kidx | y | h1 | z
    char* ws = (char*)d_ws;
    unsigned short* H = (unsigned short*)ws;
    float* dist = (float*)(ws + (size_t)NMAT * NPTS * KPACK * sizeof(unsigned short));
    float* sq   = dist + (size_t)NMAT * NPTS * NPTS;
    int*   kidx = (int*)(sq + NMAT * NPTS);
    float* ybuf = (float*)(kidx + NMAT * NPTS * KNN);
    float* h1b  = ybuf + (size_t)NMAT * NPTS * HID;
    float* zb   = h1b + (size_t)NMAT * NPTS * HID;

    split_ymlp_kernel<<<NMAT * NPTS / 64, 256, 0, stream>>>(f1, f2, W1a, H, sq, ybuf);
    gram_mfma_kernel<<<NMAT * 72, 256, 0, stream>>>(H, sq, dist);   // 1152 half-tiles
    topk_kernel<<<NMAT * NPTS / 4, 256, 0, stream>>>(dist, kidx);
    t1h1_kernel<<<NMAT * NPTS / 64, 256, 0, stream>>>(ybuf, kidx, W2a, b1a, b2a, h1b);
    t2z_kernel<<<NMAT * NPTS / 64, 256, 0, stream>>>(h1b, kidx, W1b, b1b, W2b, b2b, zb);
    sim_kernel<<<BATCH * 256, 256, 0, stream>>>(zb, dist);                      // dist := logits
    softmax_kernel<<<BATCH * NPTS, 256, 0, stream>>>(dist, out);
}

// Round 10
// 504.757 us; speedup vs baseline: 1.5302x; 1.0517x over previous
//
#include <hip/hip_runtime.h>
#include <hip/hip_bf16.h>
#include <math.h>

#define BATCH 8
#define NPTS  1024
#define DIM   1024
#define HID   64
#define KNN   20
#define NMAT  16
#define KPACK 3072   // 3 bf16 segments stored contiguously per row: k = seg*1024 + d

typedef __attribute__((ext_vector_type(8))) short short8;
typedef __attribute__((ext_vector_type(4))) float floatx4;

__device__ __forceinline__ const float* mat_base(const float* f1, const float* f2, int m) {
    return (m < BATCH) ? (f1 + (size_t)m * NPTS * DIM)
                       : (f2 + (size_t)(m - BATCH) * NPTS * DIM);
}

__device__ __forceinline__ unsigned short f2bf_bits(float v) {
    __hip_bfloat16 h = __float2bfloat16(v);   // RNE
    return *(unsigned short*)&h;
}
__device__ __forceinline__ float bfbits2f(unsigned short b) {
    union { unsigned u; float f; } c; c.u = ((unsigned)b) << 16; return c.f;
}

// ---------------- K1: FUSED 3-way bf16 split + squared norms + y = f @ W1a ----------------
// R10: 512-thread restructure. Old: 256 threads, 256 blocks = 1 block/CU = 1 wave/SIMD,
// 128 barriers — y-GEMM latency fully exposed. New: 512 threads (8 waves/CU = 2/SIMD),
// 32-k chunks (64 barriers), 8 threads/row loads (64B store segments). y accumulation
// order unchanged (ascending k, one fma per k per output) -> y bitwise identical.
// H bits elementwise-identical. sq: 8 partials/row instead of 4 (reassociation —
// precedent R1; ~1e-4, feeds dist via sq[i]+sq[j]).
__global__ __launch_bounds__(512) void split_ymlp_kernel(const float* __restrict__ f1,
                                                         const float* __restrict__ f2,
                                                         const float* __restrict__ W,
                                                         unsigned short* __restrict__ H,
                                                         float* __restrict__ sq,
                                                         float* __restrict__ y) {
    int row0 = blockIdx.x * 64;                 // 64-row blocks never straddle matrices
    int m = row0 >> 10;
    const float* A = mat_base(f1, f2, m) + (size_t)(row0 & (NPTS - 1)) * DIM;
    unsigned short* Hb = H + (size_t)row0 * KPACK;
    __shared__ float As[64][36];                // 32 k-cols + 4 pad
    __shared__ float Ws[32][68];                // 32 k-rows x 64 cols + 4 pad
    int tid = threadIdx.x;                      // 0..511
    int r = tid >> 3, cq = (tid & 7) * 4;       // load map: row r (8 thr/row), cols cq..cq+3
    int ty = tid >> 4, tx = tid & 15;           // GEMM map: rows ty*2..+1, cols tx*4..+3
    float acc[2][4];
    #pragma unroll
    for (int i = 0; i < 2; ++i)
        #pragma unroll
        for (int j = 0; j < 4; ++j) acc[i][j] = 0.f;
    float sqp = 0.f;
    unsigned short* Hr = Hb + (size_t)r * KPACK + cq;

    for (int kk = 0; kk < DIM; kk += 32) {
        float4 a = *(const float4*)&A[(size_t)r * DIM + kk + cq];
        // ---- split (bitwise-identical elementwise chain) ----
        {
            float vv[4] = {a.x, a.y, a.z, a.w};
            unsigned short h1[4], h2[4], h3[4];
            #pragma unroll
            for (int c = 0; c < 4; ++c) {
                unsigned short b1 = f2bf_bits(vv[c]);
                float r1 = vv[c] - bfbits2f(b1);
                unsigned short b2 = f2bf_bits(r1);
                float r2 = r1 - bfbits2f(b2);
                unsigned short b3 = f2bf_bits(r2);
                h1[c] = b1; h2[c] = b2; h3[c] = b3;
            }
            *(ushort4*)&Hr[kk]        = *(ushort4*)&h1[0];
            *(ushort4*)&Hr[1024 + kk] = *(ushort4*)&h2[0];
            *(ushort4*)&Hr[2048 + kk] = *(ushort4*)&h3[0];
            sqp += a.x * a.x + a.y * a.y + a.z * a.z + a.w * a.w;
        }
        // ---- GEMM staging ----
        *(float4*)&As[r][cq] = a;
        {
            int d = tid >> 4, hh = (tid & 15) * 4;   // 32 k-rows x 16 col-groups
            *(float4*)&Ws[d][hh] = *(const float4*)&W[(size_t)(kk + d) * HID + hh];
        }
        __syncthreads();
        #pragma unroll
        for (int k = 0; k < 32; ++k) {
            float av[2];
            #pragma unroll
            for (int ii = 0; ii < 2; ++ii) av[ii] = As[ty * 2 + ii][k];
            float4 w = *(const float4*)&Ws[k][tx * 4];
            #pragma unroll
            for (int ii = 0; ii < 2; ++ii) {
                acc[ii][0] += av[ii] * w.x;
                acc[ii][1] += av[ii] * w.y;
                acc[ii][2] += av[ii] * w.z;
                acc[ii][3] += av[ii] * w.w;
            }
        }
        __syncthreads();
    }
    // sq: combine the 8 per-thread partials of each row (lanes 8r..8r+7 contiguous)
    sqp += __shfl_down(sqp, 4);
    sqp += __shfl_down(sqp, 2);
    sqp += __shfl_down(sqp, 1);
    if ((tid & 7) == 0) sq[row0 + r] = sqp;
    #pragma unroll
    for (int ii = 0; ii < 2; ++ii)
        *(float4*)&y[(size_t)(row0 + ty * 2 + ii) * HID + tx * 4] = *(float4*)&acc[ii][0];
}

// ---------------- K2: Gram -> squared distances via bf16 MFMA ----------------
// R10 gram: R3 geometry RESTORED (128x128 upper-tri tiles, 576 blocks, triple-buffer
// 3x24KB, vmcnt(24), bounds(256,2) — proven 183.7us) + R9's prologue-drain fix
// (grouped prologue + vmcnt(0); removes the latent slice-0 race R8 exposed).
// R9 lesson: 128x64 retile raised occupancy 14->26% but staged bytes x1.5 and FETCH x2
// (L2 thrash) -> net loss. gram_time ~ staged_bytes / (4.9..6.4 TB/s); 128^2 is the
// best bytes/occupancy trade found. Bounds-3 forbidden (R6 flake).
#define GRAM_STEP(CURAF, NXTAF, CBUF, NBUF, KN, ISSUE, WAITOP)                             \
  {                                                                                        \
    if (ISSUE) {                                                                           \
      _Pragma("unroll")                                                                    \
      for (int s = 0; s < 3; ++s)                                                          \
        _Pragma("unroll")                                                                  \
        for (int a = 0; a < 2; ++a)                                                        \
          NXTAF[s][a] = *(const short8*)&Hm[(size_t)(ti + ((w << 1) + a) * 16 + r16) * KPACK \
                                            + (size_t)(s << 10) + (KN) + (kc << 3)];       \
      _Pragma("unroll")                                                                    \
      for (int c = 0; c < 6; ++c) {                                                        \
        int ca = w * 6 + c; int seg = ca >> 3; int rb = ca & 7;                            \
        const unsigned short* gb = Hm + (size_t)(tj + rb * 16 + r16) * KPACK               \
                                      + (size_t)(seg << 10) + (KN) + (kc << 3);            \
        __builtin_amdgcn_global_load_lds(                                                  \
            (const __attribute__((address_space(1))) void*)gb,                             \
            (__attribute__((address_space(3))) void*)&Bsl[NBUF][ca * 512], 16, 0, 0);      \
      }                                                                                    \
    }                                                                                      \
    asm volatile(WAITOP ::: "memory");                                                     \
    __builtin_amdgcn_s_barrier();                                                          \
    asm volatile("" ::: "memory");                                                         \
    __builtin_amdgcn_s_setprio(1);                                                         \
    _Pragma("unroll")                                                                      \
    for (int sb = 0; sb < 3; ++sb) {                                                       \
      short8 bf[8];                                                                        \
      _Pragma("unroll")                                                                    \
      for (int b = 0; b < 8; ++b)                                                          \
        bf[b] = *(const short8*)&Bsl[CBUF][(sb * 8 + b) * 512 + lane * 8];                 \
      _Pragma("unroll")                                                                    \
      for (int sa = 0; sa < 3; ++sa) {                                                     \
        if (sa + sb > 2) continue;                                                         \
        _Pragma("unroll")                                                                  \
        for (int a = 0; a < 2; ++a)                                                        \
          _Pragma("unroll")                                                                \
          for (int b = 0; b < 8; ++b)                                                      \
            acc[a][b] = __builtin_amdgcn_mfma_f32_16x16x32_bf16(CURAF[sa][a], bf[b],       \
                                                                acc[a][b], 0, 0, 0);       \
      }                                                                                    \
    }                                                                                      \
    __builtin_amdgcn_s_setprio(0);                                                         \
    asm volatile("" ::: "memory");                                                         \
    __builtin_amdgcn_s_barrier();                                                          \
  }

__global__ __launch_bounds__(256, 2) void gram_mfma_kernel(const unsigned short* __restrict__ H,
                                                           const float* __restrict__ sq,
                                                           float* __restrict__ dist) {
    int bid = blockIdx.x;
    int xcd = bid & 7;
    int g = bid >> 3;                 // 0..71
    int m = xcd + 8 * (g & 1);        // interleave this XCD's two matrices
    int t = g >> 1;                   // 0..35
    int bi = 0;
    { int a = t; while (a >= 8 - bi) { a -= 8 - bi; ++bi; } t = a; }
    int bj = bi + t;
    int ti = bi << 7, tj = bj << 7;

    const unsigned short* Hm = H + (size_t)m * NPTS * KPACK;

    // B chunks: ca = seg*8 + colblk ; each chunk: [lane(64)][8 shorts] = 1KB (16 cols x 32 k)
    __shared__ __align__(16) unsigned short Bsl[3][24 * 512];   // 3 x 24 KB triple buffer

    int tid = threadIdx.x;
    int w = tid >> 6, lane = tid & 63;
    int r16 = lane & 15, kc = lane >> 4;

    floatx4 acc[2][8];
    #pragma unroll
    for (int a = 0; a < 2; ++a)
        #pragma unroll
        for (int b = 0; b < 8; ++b) acc[a][b] = (floatx4)0.f;

    // A fragment triple buffers: wave-disjoint rows ti + w*32 .. +31 (3 segs x 2 rowblocks)
    short8 afA[3][2], afB[3][2], afC[3][2];

    // ---- prologue (grouped: afA | B0-DMA | afB | B1-DMA, then full drain — R9 fix) ----
    #pragma unroll
    for (int s = 0; s < 3; ++s)
        #pragma unroll
        for (int a = 0; a < 2; ++a)
            afA[s][a] = *(const short8*)&Hm[(size_t)(ti + ((w << 1) + a) * 16 + r16) * KPACK
                                            + (size_t)(s << 10) + (kc << 3)];
    asm volatile("" ::: "memory");
    #pragma unroll
    for (int c = 0; c < 6; ++c) {
        int ca = w * 6 + c; int seg = ca >> 3; int rb = ca & 7;
        const unsigned short* gb = Hm + (size_t)(tj + rb * 16 + r16) * KPACK
                                      + (size_t)(seg << 10) + (kc << 3);
        __builtin_amdgcn_global_load_lds(
            (const __attribute__((address_space(1))) void*)gb,
            (__attribute__((address_space(3))) void*)&Bsl[0][ca * 512], 16, 0, 0);
    }
    asm volatile("" ::: "memory");
    #pragma unroll
    for (int s = 0; s < 3; ++s)
        #pragma unroll
        for (int a = 0; a < 2; ++a)
            afB[s][a] = *(const short8*)&Hm[(size_t)(ti + ((w << 1) + a) * 16 + r16) * KPACK
                                            + (size_t)(s << 10) + 32 + (kc << 3)];
    asm volatile("" ::: "memory");
    #pragma unroll
    for (int c = 0; c < 6; ++c) {
        int ca = w * 6 + c; int seg = ca >> 3; int rb = ca & 7;
        const unsigned short* gb = Hm + (size_t)(tj + rb * 16 + r16) * KPACK
                                      + (size_t)(seg << 10) + 32 + (kc << 3);
        __builtin_amdgcn_global_load_lds(
            (const __attribute__((address_space(1))) void*)gb,
            (__attribute__((address_space(3))) void*)&Bsl[1][ca * 512], 16, 0, 0);
    }
    // Full drain: slices 0/1 complete before the loop; steps 0/1's vmcnt(24) are
    // no-ops (12/24 outstanding); steady state from step 2 retires exactly one slice.
    asm volatile("s_waitcnt vmcnt(0)" ::: "memory");

    // slices 0..29: compute t, issue t+2, wait vmcnt(24) (t+1,t+2 in flight: 12+12)
    #pragma unroll 1
    for (int t2 = 0; t2 < 30; t2 += 3) {
        GRAM_STEP(afA, afC, 0, 2, (t2 + 2) * 32, 1, "s_waitcnt vmcnt(24)");
        GRAM_STEP(afB, afA, 1, 0, (t2 + 3) * 32, 1, "s_waitcnt vmcnt(24)");
        GRAM_STEP(afC, afB, 2, 1, (t2 + 4) * 32, 1, "s_waitcnt vmcnt(24)");
    }
    // epilogue: slice 30 (slice 31 still in flight), then slice 31
    GRAM_STEP(afA, afC, 0, 2, 0, 0, "s_waitcnt vmcnt(12)");
    GRAM_STEP(afB, afC, 1, 2, 0, 0, "s_waitcnt vmcnt(0)");

    const float* sqm = sq + m * NPTS;
    #pragma unroll
    for (int a = 0; a < 2; ++a) {
        int i0 = ti + ((w << 1) + a) * 16 + (lane >> 4) * 4;
        #pragma unroll
        for (int b = 0; b < 8; ++b) {
            int j = tj + b * 16 + (lane & 15);
            float sqj = sqm[j];
            #pragma unroll
            for (int r = 0; r < 4; ++r) {
                int i = i0 + r;
                float v = sqm[i] + sqj - 2.f * acc[a][b][r];
                if (i == j) v += 1e10f;
                dist[((size_t)m * NPTS + i) * NPTS + j] = v;
                if (bi != bj) dist[((size_t)m * NPTS + j) * NPTS + i] = v;
            }
        }
    }
}

// ---------------- K3: top-k (k=20 smallest), one wave per row, all-register ----------------
__global__ __launch_bounds__(256) void topk_kernel(const float* __restrict__ dist,
                                                   int* __restrict__ knn_idx) {
    int tid = threadIdx.x;
    int wave = tid >> 6, lane = tid & 63;
    int row = blockIdx.x * 4 + wave;
    const float* d = dist + (size_t)row * NPTS;
    float v[16];
    #pragma unroll
    for (int s = 0; s < 16; ++s) v[s] = d[s * 64 + lane];
    int myj = 0;
    for (int sel = 0; sel < KNN; ++sel) {
        float bv = v[0]; int bs = 0;
        #pragma unroll
        for (int s = 1; s < 16; ++s)
            if (v[s] < bv) { bv = v[s]; bs = s; }   // ascending s: lowest j locally on ties
        int bj = bs * 64 + lane;
        #pragma unroll
        for (int off = 1; off < 64; off <<= 1) {
            float ov = __shfl_xor(bv, off);
            int   oj = __shfl_xor(bj, off);
            if (ov < bv || (ov == bv && oj < bj)) { bv = ov; bj = oj; }
        }
        if ((bj & 63) == lane) v[bj >> 6] = 3e38f;  // owner clears
        if (lane == sel) myj = bj;
    }
    if (lane < KNN) knn_idx[(size_t)row * KNN + lane] = myj;
}

// ---------------- K5: t1 = relu(y_i + sum y_n + b1a); h1 = t1 @ W2a + b2a ----------------
__global__ __launch_bounds__(256) void t1h1_kernel(const float* __restrict__ y,
                                                   const int* __restrict__ knn_idx,
                                                   const float* __restrict__ W,
                                                   const float* __restrict__ bias1,
                                                   const float* __restrict__ bias2,
                                                   float* __restrict__ h1) {
    int row0 = blockIdx.x * 64;
    int m = row0 >> 10;
    __shared__ int nb[64 * KNN];
    __shared__ float t1s[64][65];
    __shared__ float Ws[64][HID];
    __shared__ float b1s[HID], b2s[HID];
    int tid = threadIdx.x;
    for (int k = tid; k < 64 * KNN; k += 256) nb[k] = knn_idx[(size_t)row0 * KNN + k];
    for (int k = tid; k < 64 * HID; k += 256) Ws[k >> 6][k & 63] = W[k];
    if (tid < HID) { b1s[tid] = bias1[tid]; b2s[tid] = bias2[tid]; }
    __syncthreads();
    {
        int r = tid >> 2, c0 = (tid & 3) * 16;
        const float* yr = y + (size_t)(row0 + r) * HID + c0;
        float4 a[4];
        #pragma unroll
        for (int q = 0; q < 4; ++q) a[q] = *(const float4*)&yr[q * 4];
        const float* ym = y + (size_t)(m << 10) * HID;
        #pragma unroll
        for (int t = 0; t < KNN; ++t) {
            const float* yn = ym + (size_t)nb[r * KNN + t] * HID + c0;
            #pragma unroll
            for (int q = 0; q < 4; ++q) {
                float4 v = *(const float4*)&yn[q * 4];
                a[q].x += v.x; a[q].y += v.y; a[q].z += v.z; a[q].w += v.w;
            }
        }
        #pragma unroll
        for (int q = 0; q < 4; ++q) {
            int c = c0 + q * 4;
            t1s[r][c + 0] = fmaxf(a[q].x + b1s[c + 0], 0.f);
            t1s[r][c + 1] = fmaxf(a[q].y + b1s[c + 1], 0.f);
            t1s[r][c + 2] = fmaxf(a[q].z + b1s[c + 2], 0.f);
            t1s[r][c + 3] = fmaxf(a[q].w + b1s[c + 3], 0.f);
        }
    }
    __syncthreads();
    int ty = tid >> 4, tx = tid & 15;
    float acc[4][4];
    #pragma unroll
    for (int i = 0; i < 4; ++i)
        #pragma unroll
        for (int j = 0; j < 4; ++j) acc[i][j] = 0.f;
    #pragma unroll
    for (int k = 0; k < HID; ++k) {
        float a[4];
        #pragma unroll
        for (int ii = 0; ii < 4; ++ii) a[ii] = t1s[ty * 4 + ii][k];
        float4 w = *(const float4*)&Ws[k][tx * 4];
        #pragma unroll
        for (int ii = 0; ii < 4; ++ii) {
            acc[ii][0] += a[ii] * w.x;
            acc[ii][1] += a[ii] * w.y;
            acc[ii][2] += a[ii] * w.z;
            acc[ii][3] += a[ii] * w.w;
        }
    }
    #pragma unroll
    for (int ii = 0; ii < 4; ++ii) {
        float o[4];
        #pragma unroll
        for (int jj = 0; jj < 4; ++jj) o[jj] = acc[ii][jj] + b2s[tx * 4 + jj];
        *(float4*)&h1[(size_t)(row0 + ty * 4 + ii) * HID + tx * 4] = *(float4*)&o[0];
    }
}

// ---------------- K6: hs = h1_i + sum h1_n; t2 = relu(hs@W1b+b1b); z = t2@W2b+b2b ----------------
__global__ __launch_bounds__(256) void t2z_kernel(const float* __restrict__ h1,
                                                  const int* __restrict__ knn_idx,
                                                  const float* __restrict__ W1,
                                                  const float* __restrict__ bias1,
                                                  const float* __restrict__ W2,
                                                  const float* __restrict__ bias2,
                                                  float* __restrict__ z) {
    int row0 = blockIdx.x * 64;
    int m = row0 >> 10;
    __shared__ int nb[64 * KNN];
    __shared__ float hs[64][65];
    __shared__ float t2s[64][65];
    __shared__ float Ws[64][HID];
    __shared__ float b1s[HID], b2s[HID];
    int tid = threadIdx.x;
    for (int k = tid; k < 64 * KNN; k += 256) nb[k] = knn_idx[(size_t)row0 * KNN + k];
    for (int k = tid; k < 64 * HID; k += 256) Ws[k >> 6][k & 63] = W1[k];
    if (tid < HID) { b1s[tid] = bias1[tid]; b2s[tid] = bias2[tid]; }
    __syncthreads();
    {
        int r = tid >> 2, c0 = (tid & 3) * 16;
        const float* hr = h1 + (size_t)(row0 + r) * HID + c0;
        float4 a[4];
        #pragma unroll
        for (int q = 0; q < 4; ++q) a[q] = *(const float4*)&hr[q * 4];
        const float* hm = h1 + (size_t)(m << 10) * HID;
        #pragma unroll
        for (int t = 0; t < KNN; ++t) {
            const float* hn = hm + (size_t)nb[r * KNN + t] * HID + c0;
            #pragma unroll
            for (int q = 0; q < 4; ++q) {
                float4 v = *(const float4*)&hn[q * 4];
                a[q].x += v.x; a[q].y += v.y; a[q].z += v.z; a[q].w += v.w;
            }
        }
        #pragma unroll
        for (int q = 0; q < 4; ++q) *(float4*)&hs[r][c0 + q * 4] = a[q];
    }
    __syncthreads();
    int ty = tid >> 4, tx = tid & 15;
    float acc[4][4];
    #pragma unroll
    for (int i = 0; i < 4; ++i)
        #pragma unroll
        for (int j = 0; j < 4; ++j) acc[i][j] = 0.f;
    #pragma unroll
    for (int k = 0; k < HID; ++k) {
        float a[4];
        #pragma unroll
        for (int ii = 0; ii < 4; ++ii) a[ii] = hs[ty * 4 + ii][k];
        float4 w = *(const float4*)&Ws[k][tx * 4];
        #pragma unroll
        for (int ii = 0; ii < 4; ++ii) {
            acc[ii][0] += a[ii] * w.x;
            acc[ii][1] += a[ii] * w.y;
            acc[ii][2] += a[ii] * w.z;
            acc[ii][3] += a[ii] * w.w;
        }
    }
    #pragma unroll
    for (int ii = 0; ii < 4; ++ii)
        #pragma unroll
        for (int jj = 0; jj < 4; ++jj)
            t2s[ty * 4 + ii][tx * 4 + jj] = fmaxf(acc[ii][jj] + b1s[tx * 4 + jj], 0.f);
    __syncthreads();
    for (int k = tid; k < 64 * HID; k += 256) Ws[k >> 6][k & 63] = W2[k];
    __syncthreads();
    #pragma unroll
    for (int i = 0; i < 4; ++i)
        #pragma unroll
        for (int j = 0; j < 4; ++j) acc[i][j] = 0.f;
    #pragma unroll
    for (int k = 0; k < HID; ++k) {
        float a[4];
        #pragma unroll
        for (int ii = 0; ii < 4; ++ii) a[ii] = t2s[ty * 4 + ii][k];
        float4 w = *(const float4*)&Ws[k][tx * 4];
        #pragma unroll
        for (int ii = 0; ii < 4; ++ii) {
            acc[ii][0] += a[ii] * w.x;
            acc[ii][1] += a[ii] * w.y;
            acc[ii][2] += a[ii] * w.z;
            acc[ii][3] += a[ii] * w.w;
        }
    }
    #pragma unroll
    for (int ii = 0; ii < 4; ++ii) {
        float o[4];
        #pragma unroll
        for (int jj = 0; jj < 4; ++jj) o[jj] = acc[ii][jj] + b2s[tx * 4 + jj];
        *(float4*)&z[(size_t)(row0 + ty * 4 + ii) * HID + tx * 4] = *(float4*)&o[0];
    }
}

// ---------------- K7: sim = z1 @ z2^T (64x64 tiles, K=64) ----------------
__global__ __launch_bounds__(256) void sim_kernel(const float* __restrict__ z,
                                                  float* __restrict__ logits) {
    int bid = blockIdx.x;
    int b = bid >> 8;
    int tile = bid & 255;
    int ti = (tile >> 4) << 6;
    int tj = (tile & 15) << 6;
    const float* z1 = z + (size_t)b * NPTS * HID;
    const float* z2 = z + (size_t)(BATCH + b) * NPTS * HID;
    __shared__ float Z1[64][68];
    __shared__ float Z2[64][68];
    int tid = threadIdx.x;
    #pragma unroll
    for (int i = 0; i < 4; ++i) {
        int l = tid + i * 256;
        int r = l >> 4, c = (l & 15) * 4;
        *(float4*)&Z1[r][c] = *(const float4*)&z1[(size_t)(ti + r) * HID + c];
        *(float4*)&Z2[r][c] = *(const float4*)&z2[(size_t)(tj + r) * HID + c];
    }
    __syncthreads();
    int ty = tid >> 4, tx = tid & 15;
    float acc[4][4];
    #pragma unroll
    for (int i = 0; i < 4; ++i)
        #pragma unroll
        for (int j = 0; j < 4; ++j) acc[i][j] = 0.f;
    #pragma unroll
    for (int h = 0; h < HID; ++h) {
        float a[4], bb[4];
        #pragma unroll
        for (int ii = 0; ii < 4; ++ii) { a[ii] = Z1[ty * 4 + ii][h]; bb[ii] = Z2[tx * 4 + ii][h]; }
        #pragma unroll
        for (int ii = 0; ii < 4; ++ii)
            #pragma unroll
            for (int jj = 0; jj < 4; ++jj)
                acc[ii][jj] += a[ii] * bb[jj];
    }
    #pragma unroll
    for (int ii = 0; ii < 4; ++ii) {
        float* dst = logits + ((size_t)b * NPTS + ti + ty * 4 + ii) * NPTS + tj + tx * 4;
        *(float4*)&dst[0] = *(float4*)&acc[ii][0];
    }
}

// ---------------- K8: row softmax ----------------
__global__ __launch_bounds__(256) void softmax_kernel(const float* __restrict__ logits,
                                                      float* __restrict__ out) {
    int row = blockIdx.x;                         // 0..8191
    const float* L = logits + (size_t)row * NPTS;
    __shared__ float buf[NPTS];
    __shared__ float red[8];
    int tid = threadIdx.x;
    int wave = tid >> 6, lane = tid & 63;
    float mx = -3e38f;
    #pragma unroll
    for (int s = 0; s < 4; ++s) {
        float v = L[tid + s * 256];
        buf[tid + s * 256] = v;
        mx = fmaxf(mx, v);
    }
    #pragma unroll
    for (int off = 32; off > 0; off >>= 1) mx = fmaxf(mx, __shfl_down(mx, off));
    if (lane == 0) red[wave] = mx;
    __syncthreads();
    mx = fmaxf(fmaxf(red[0], red[1]), fmaxf(red[2], red[3]));
    float sum = 0.f;
    #pragma unroll
    for (int s = 0; s < 4; ++s) {
        float e = expf(buf[tid + s * 256] - mx);
        buf[tid + s * 256] = e;
        sum += e;
    }
    #pragma unroll
    for (int off = 32; off > 0; off >>= 1) sum += __shfl_down(sum, off);
    if (lane == 0) red[4 + wave] = sum;
    __syncthreads();
    float inv = 1.f / (red[4] + red[5] + red[6] + red[7]);
    #pragma unroll
    for (int s = 0; s < 4; ++s)
        out[(size_t)row * NPTS + tid + s * 256] = buf[tid + s * 256] * inv;
}

extern "C" void kernel_launch(void* const* d_in, const int* in_sizes, int n_in,
                              void* d_out, int out_size, void* d_ws, size_t ws_size,
                              hipStream_t stream) {
    const float* f1  = (const float*)d_in[0];
    const float* f2  = (const float*)d_in[1];
    const float* W1a = (const float*)d_in[2];
    const float* b1a = (const float*)d_in[3];
    const float* W2a = (const float*)d_in[4];
    const float* b2a = (const float*)d_in[5];
    const float* W1b = (const float*)d_in[6];
    const float* b1b = (const float*)d_in[7];
    const float* W2b = (const float*)d_in[8];
    const float* b2b = (const float*)d_in[9];
    float* out = (float*)d_out;

    // workspace: H packed (100.7MB) | dist (67.1MB, reused as sim logits) | sq | kidx | y | h1 | z
    char* ws = (char*)d_ws;
    unsigned short* H = (unsigned short*)ws;
    float* dist = (float*)(ws + (size_t)NMAT * NPTS * KPACK * sizeof(unsigned short));
    float* sq   = dist + (size_t)NMAT * NPTS * NPTS;
    int*   kidx = (int*)(sq + NMAT * NPTS);
    float* ybuf = (float*)(kidx + NMAT * NPTS * KNN);
    float* h1b  = ybuf + (size_t)NMAT * NPTS * HID;
    float* zb   = h1b + (size_t)NMAT * NPTS * HID;

    split_ymlp_kernel<<<NMAT * NPTS / 64, 512, 0, stream>>>(f1, f2, W1a, H, sq, ybuf);
    gram_mfma_kernel<<<NMAT * 36, 256, 0, stream>>>(H, sq, dist);
    topk_kernel<<<NMAT * NPTS / 4, 256, 0, stream>>>(dist, kidx);
    t1h1_kernel<<<NMAT * NPTS / 64, 256, 0, stream>>>(ybuf, kidx, W2a, b1a, b2a, h1b);
    t2z_kernel<<<NMAT * NPTS / 64, 256, 0, stream>>>(h1b, kidx, W1b, b1b, W2b, b2b, zb);
    sim_kernel<<<BATCH * 256, 256, 0, stream>>>(zb, dist);                      // dist := logits
    softmax_kernel<<<BATCH * NPTS, 256, 0, stream>>>(dist, out);
}

// Round 11
// 497.828 us; speedup vs baseline: 1.5515x; 1.0139x over previous
//
#include <hip/hip_runtime.h>
#include <hip/hip_bf16.h>
#include <math.h>

#define BATCH 8
#define NPTS  1024
#define DIM   1024
#define HID   64
#define KNN   20
#define NMAT  16
#define KPACK 3072   // 3 bf16 segments stored contiguously per row: k = seg*1024 + d

typedef __attribute__((ext_vector_type(8))) short short8;
typedef __attribute__((ext_vector_type(4))) float floatx4;

__device__ __forceinline__ const float* mat_base(const float* f1, const float* f2, int m) {
    return (m < BATCH) ? (f1 + (size_t)m * NPTS * DIM)
                       : (f2 + (size_t)(m - BATCH) * NPTS * DIM);
}

__device__ __forceinline__ unsigned short f2bf_bits(float v) {
    __hip_bfloat16 h = __float2bfloat16(v);   // RNE
    return *(unsigned short*)&h;
}
__device__ __forceinline__ float bfbits2f(unsigned short b) {
    union { unsigned u; float f; } c; c.u = ((unsigned)b) << 16; return c.f;
}

// ---------------- K1: FUSED 3-way bf16 split + squared norms + y = f @ W1a ----------------
// R10 version (proven): 512 threads, 32-k chunks, 8 waves/CU.
__global__ __launch_bounds__(512) void split_ymlp_kernel(const float* __restrict__ f1,
                                                         const float* __restrict__ f2,
                                                         const float* __restrict__ W,
                                                         unsigned short* __restrict__ H,
                                                         float* __restrict__ sq,
                                                         float* __restrict__ y) {
    int row0 = blockIdx.x * 64;                 // 64-row blocks never straddle matrices
    int m = row0 >> 10;
    const float* A = mat_base(f1, f2, m) + (size_t)(row0 & (NPTS - 1)) * DIM;
    unsigned short* Hb = H + (size_t)row0 * KPACK;
    __shared__ float As[64][36];                // 32 k-cols + 4 pad
    __shared__ float Ws[32][68];                // 32 k-rows x 64 cols + 4 pad
    int tid = threadIdx.x;                      // 0..511
    int r = tid >> 3, cq = (tid & 7) * 4;       // load map: row r (8 thr/row), cols cq..cq+3
    int ty = tid >> 4, tx = tid & 15;           // GEMM map: rows ty*2..+1, cols tx*4..+3
    float acc[2][4];
    #pragma unroll
    for (int i = 0; i < 2; ++i)
        #pragma unroll
        for (int j = 0; j < 4; ++j) acc[i][j] = 0.f;
    float sqp = 0.f;
    unsigned short* Hr = Hb + (size_t)r * KPACK + cq;

    for (int kk = 0; kk < DIM; kk += 32) {
        float4 a = *(const float4*)&A[(size_t)r * DIM + kk + cq];
        // ---- split (bitwise-identical elementwise chain) ----
        {
            float vv[4] = {a.x, a.y, a.z, a.w};
            unsigned short h1[4], h2[4], h3[4];
            #pragma unroll
            for (int c = 0; c < 4; ++c) {
                unsigned short b1 = f2bf_bits(vv[c]);
                float r1 = vv[c] - bfbits2f(b1);
                unsigned short b2 = f2bf_bits(r1);
                float r2 = r1 - bfbits2f(b2);
                unsigned short b3 = f2bf_bits(r2);
                h1[c] = b1; h2[c] = b2; h3[c] = b3;
            }
            *(ushort4*)&Hr[kk]        = *(ushort4*)&h1[0];
            *(ushort4*)&Hr[1024 + kk] = *(ushort4*)&h2[0];
            *(ushort4*)&Hr[2048 + kk] = *(ushort4*)&h3[0];
            sqp += a.x * a.x + a.y * a.y + a.z * a.z + a.w * a.w;
        }
        // ---- GEMM staging ----
        *(float4*)&As[r][cq] = a;
        {
            int d = tid >> 4, hh = (tid & 15) * 4;   // 32 k-rows x 16 col-groups
            *(float4*)&Ws[d][hh] = *(const float4*)&W[(size_t)(kk + d) * HID + hh];
        }
        __syncthreads();
        #pragma unroll
        for (int k = 0; k < 32; ++k) {
            float av[2];
            #pragma unroll
            for (int ii = 0; ii < 2; ++ii) av[ii] = As[ty * 2 + ii][k];
            float4 w = *(const float4*)&Ws[k][tx * 4];
            #pragma unroll
            for (int ii = 0; ii < 2; ++ii) {
                acc[ii][0] += av[ii] * w.x;
                acc[ii][1] += av[ii] * w.y;
                acc[ii][2] += av[ii] * w.z;
                acc[ii][3] += av[ii] * w.w;
            }
        }
        __syncthreads();
    }
    sqp += __shfl_down(sqp, 4);
    sqp += __shfl_down(sqp, 2);
    sqp += __shfl_down(sqp, 1);
    if ((tid & 7) == 0) sq[row0 + r] = sqp;
    #pragma unroll
    for (int ii = 0; ii < 2; ++ii)
        *(float4*)&y[(size_t)(row0 + ty * 2 + ii) * HID + tx * 4] = *(float4*)&acc[ii][0];
}

// ---------------- K2: Gram -> squared distances via bf16 MFMA ----------------
// R11: 512-thread blocks (8 waves, wave owns 16 rows x 128 cols) -> 16 waves/CU at
// bounds(512,4), same 128^2 tiles, same bytes (884MB). Evidence (R10 occupancy math):
// T_block ~90us is a latency-structural floor at 4 waves/CU — round-2 solo blocks run
// as slow as round-1 fabric-saturated ones. Doubling waves/CU attacks the stall with
// TLP at zero byte cost; tail blocks also run 2x-waves. Per wave/slice: 3 A-reg loads
// + 3 B-DMAs -> steady vmcnt(12), epilogue 6->0; R9-proven grouped prologue + vmcnt(0)
// drain (counts re-verified: step0/1 waits are no-ops on drained slices 0/1; steady
// step t retires exactly slice t's 6). B-chunk layout (ca=seg*8+colblk), (sb,sa)
// product order, slice order, C-map unchanged -> dist bitwise identical to R10.
// acc[8]x4 + af[3]x3bufs ~= 120 VGPR <= 128 (4 waves/SIMD budget).
#define GRAM_STEP(CURAF, NXTAF, CBUF, NBUF, KN, ISSUE, WAITOP)                             \
  {                                                                                        \
    if (ISSUE) {                                                                           \
      _Pragma("unroll")                                                                    \
      for (int s = 0; s < 3; ++s)                                                          \
        NXTAF[s] = *(const short8*)&Hm[(size_t)(ti + (w << 4) + r16) * KPACK               \
                                       + (size_t)(s << 10) + (KN) + (kc << 3)];            \
      _Pragma("unroll")                                                                    \
      for (int c = 0; c < 3; ++c) {                                                        \
        int ca = w * 3 + c; int seg = ca >> 3; int rb = ca & 7;                            \
        const unsigned short* gb = Hm + (size_t)(tj + rb * 16 + r16) * KPACK               \
                                      + (size_t)(seg << 10) + (KN) + (kc << 3);            \
        __builtin_amdgcn_global_load_lds(                                                  \
            (const __attribute__((address_space(1))) void*)gb,                             \
            (__attribute__((address_space(3))) void*)&Bsl[NBUF][ca * 512], 16, 0, 0);      \
      }                                                                                    \
    }                                                                                      \
    asm volatile(WAITOP ::: "memory");                                                     \
    __builtin_amdgcn_s_barrier();                                                          \
    asm volatile("" ::: "memory");                                                         \
    __builtin_amdgcn_s_setprio(1);                                                         \
    _Pragma("unroll")                                                                      \
    for (int sb = 0; sb < 3; ++sb) {                                                       \
      short8 bf[8];                                                                        \
      _Pragma("unroll")                                                                    \
      for (int b = 0; b < 8; ++b)                                                          \
        bf[b] = *(const short8*)&Bsl[CBUF][(sb * 8 + b) * 512 + lane * 8];                 \
      _Pragma("unroll")                                                                    \
      for (int sa = 0; sa < 3; ++sa) {                                                     \
        if (sa + sb > 2) continue;                                                         \
        _Pragma("unroll")                                                                  \
        for (int b = 0; b < 8; ++b)                                                        \
          acc[b] = __builtin_amdgcn_mfma_f32_16x16x32_bf16(CURAF[sa], bf[b],               \
                                                           acc[b], 0, 0, 0);               \
      }                                                                                    \
    }                                                                                      \
    __builtin_amdgcn_s_setprio(0);                                                         \
    asm volatile("" ::: "memory");                                                         \
    __builtin_amdgcn_s_barrier();                                                          \
  }

__global__ __launch_bounds__(512, 4) void gram_mfma_kernel(const unsigned short* __restrict__ H,
                                                           const float* __restrict__ sq,
                                                           float* __restrict__ dist) {
    int bid = blockIdx.x;
    int xcd = bid & 7;
    int g = bid >> 3;                 // 0..71
    int m = xcd + 8 * (g & 1);        // interleave this XCD's two matrices
    int t = g >> 1;                   // 0..35
    int bi = 0;
    { int a = t; while (a >= 8 - bi) { a -= 8 - bi; ++bi; } t = a; }
    int bj = bi + t;
    int ti = bi << 7, tj = bj << 7;

    const unsigned short* Hm = H + (size_t)m * NPTS * KPACK;

    // B chunks: ca = seg*8 + colblk ; each chunk: [lane(64)][8 shorts] = 1KB (16 cols x 32 k)
    __shared__ __align__(16) unsigned short Bsl[3][24 * 512];   // 3 x 24 KB triple buffer

    int tid = threadIdx.x;
    int w = tid >> 6, lane = tid & 63;   // 8 waves; wave owns rows ti + w*16 .. +15
    int r16 = lane & 15, kc = lane >> 4;

    floatx4 acc[8];
    #pragma unroll
    for (int b = 0; b < 8; ++b) acc[b] = (floatx4)0.f;

    // A fragment triple buffers: wave-private rows (3 segs x 1 rowblock each)
    short8 afA[3], afB[3], afC[3];

    // ---- prologue (grouped: afA | B0-DMA | afB | B1-DMA, then full drain) ----
    #pragma unroll
    for (int s = 0; s < 3; ++s)
        afA[s] = *(const short8*)&Hm[(size_t)(ti + (w << 4) + r16) * KPACK
                                     + (size_t)(s << 10) + (kc << 3)];
    asm volatile("" ::: "memory");
    #pragma unroll
    for (int c = 0; c < 3; ++c) {
        int ca = w * 3 + c; int seg = ca >> 3; int rb = ca & 7;
        const unsigned short* gb = Hm + (size_t)(tj + rb * 16 + r16) * KPACK
                                      + (size_t)(seg << 10) + (kc << 3);
        __builtin_amdgcn_global_load_lds(
            (const __attribute__((address_space(1))) void*)gb,
            (__attribute__((address_space(3))) void*)&Bsl[0][ca * 512], 16, 0, 0);
    }
    asm volatile("" ::: "memory");
    #pragma unroll
    for (int s = 0; s < 3; ++s)
        afB[s] = *(const short8*)&Hm[(size_t)(ti + (w << 4) + r16) * KPACK
                                     + (size_t)(s << 10) + 32 + (kc << 3)];
    asm volatile("" ::: "memory");
    #pragma unroll
    for (int c = 0; c < 3; ++c) {
        int ca = w * 3 + c; int seg = ca >> 3; int rb = ca & 7;
        const unsigned short* gb = Hm + (size_t)(tj + rb * 16 + r16) * KPACK
                                      + (size_t)(seg << 10) + 32 + (kc << 3);
        __builtin_amdgcn_global_load_lds(
            (const __attribute__((address_space(1))) void*)gb,
            (__attribute__((address_space(3))) void*)&Bsl[1][ca * 512], 16, 0, 0);
    }
    // Full drain: slices 0/1 complete before the loop; steps 0/1's vmcnt(12) are
    // no-ops (6/12 outstanding); steady state from step 2 retires exactly one slice.
    asm volatile("s_waitcnt vmcnt(0)" ::: "memory");

    // slices 0..29: compute t, issue t+2, wait vmcnt(12) (t+1,t+2 in flight: 6+6)
    #pragma unroll 1
    for (int t2 = 0; t2 < 30; t2 += 3) {
        GRAM_STEP(afA, afC, 0, 2, (t2 + 2) * 32, 1, "s_waitcnt vmcnt(12)");
        GRAM_STEP(afB, afA, 1, 0, (t2 + 3) * 32, 1, "s_waitcnt vmcnt(12)");
        GRAM_STEP(afC, afB, 2, 1, (t2 + 4) * 32, 1, "s_waitcnt vmcnt(12)");
    }
    // epilogue: slice 30 (slice 31 still in flight), then slice 31
    GRAM_STEP(afA, afC, 0, 2, 0, 0, "s_waitcnt vmcnt(6)");
    GRAM_STEP(afB, afC, 1, 2, 0, 0, "s_waitcnt vmcnt(0)");

    const float* sqm = sq + m * NPTS;
    {
        int i0 = ti + (w << 4) + (lane >> 4) * 4;
        #pragma unroll
        for (int b = 0; b < 8; ++b) {
            int j = tj + b * 16 + (lane & 15);
            float sqj = sqm[j];
            #pragma unroll
            for (int r = 0; r < 4; ++r) {
                int i = i0 + r;
                float v = sqm[i] + sqj - 2.f * acc[b][r];
                if (i == j) v += 1e10f;
                dist[((size_t)m * NPTS + i) * NPTS + j] = v;
                if (bi != bj) dist[((size_t)m * NPTS + j) * NPTS + i] = v;
            }
        }
    }
}

// ---------------- K3: top-k (k=20 smallest), one wave per row, all-register ----------------
__global__ __launch_bounds__(256) void topk_kernel(const float* __restrict__ dist,
                                                   int* __restrict__ knn_idx) {
    int tid = threadIdx.x;
    int wave = tid >> 6, lane = tid & 63;
    int row = blockIdx.x * 4 + wave;
    const float* d = dist + (size_t)row * NPTS;
    float v[16];
    #pragma unroll
    for (int s = 0; s < 16; ++s) v[s] = d[s * 64 + lane];
    int myj = 0;
    for (int sel = 0; sel < KNN; ++sel) {
        float bv = v[0]; int bs = 0;
        #pragma unroll
        for (int s = 1; s < 16; ++s)
            if (v[s] < bv) { bv = v[s]; bs = s; }   // ascending s: lowest j locally on ties
        int bj = bs * 64 + lane;
        #pragma unroll
        for (int off = 1; off < 64; off <<= 1) {
            float ov = __shfl_xor(bv, off);
            int   oj = __shfl_xor(bj, off);
            if (ov < bv || (ov == bv && oj < bj)) { bv = ov; bj = oj; }
        }
        if ((bj & 63) == lane) v[bj >> 6] = 3e38f;  // owner clears
        if (lane == sel) myj = bj;
    }
    if (lane < KNN) knn_idx[(size_t)row * KNN + lane] = myj;
}

// ---------------- K5: t1 = relu(y_i + sum y_n + b1a); h1 = t1 @ W2a + b2a ----------------
__global__ __launch_bounds__(256) void t1h1_kernel(const float* __restrict__ y,
                                                   const int* __restrict__ knn_idx,
                                                   const float* __restrict__ W,
                                                   const float* __restrict__ bias1,
                                                   const float* __restrict__ bias2,
                                                   float* __restrict__ h1) {
    int row0 = blockIdx.x * 64;
    int m = row0 >> 10;
    __shared__ int nb[64 * KNN];
    __shared__ float t1s[64][65];
    __shared__ float Ws[64][HID];
    __shared__ float b1s[HID], b2s[HID];
    int tid = threadIdx.x;
    for (int k = tid; k < 64 * KNN; k += 256) nb[k] = knn_idx[(size_t)row0 * KNN + k];
    for (int k = tid; k < 64 * HID; k += 256) Ws[k >> 6][k & 63] = W[k];
    if (tid < HID) { b1s[tid] = bias1[tid]; b2s[tid] = bias2[tid]; }
    __syncthreads();
    {
        int r = tid >> 2, c0 = (tid & 3) * 16;
        const float* yr = y + (size_t)(row0 + r) * HID + c0;
        float4 a[4];
        #pragma unroll
        for (int q = 0; q < 4; ++q) a[q] = *(const float4*)&yr[q * 4];
        const float* ym = y + (size_t)(m << 10) * HID;
        #pragma unroll
        for (int t = 0; t < KNN; ++t) {
            const float* yn = ym + (size_t)nb[r * KNN + t] * HID + c0;
            #pragma unroll
            for (int q = 0; q < 4; ++q) {
                float4 v = *(const float4*)&yn[q * 4];
                a[q].x += v.x; a[q].y += v.y; a[q].z += v.z; a[q].w += v.w;
            }
        }
        #pragma unroll
        for (int q = 0; q < 4; ++q) {
            int c = c0 + q * 4;
            t1s[r][c + 0] = fmaxf(a[q].x + b1s[c + 0], 0.f);
            t1s[r][c + 1] = fmaxf(a[q].y + b1s[c + 1], 0.f);
            t1s[r][c + 2] = fmaxf(a[q].z + b1s[c + 2], 0.f);
            t1s[r][c + 3] = fmaxf(a[q].w + b1s[c + 3], 0.f);
        }
    }
    __syncthreads();
    int ty = tid >> 4, tx = tid & 15;
    float acc[4][4];
    #pragma unroll
    for (int i = 0; i < 4; ++i)
        #pragma unroll
        for (int j = 0; j < 4; ++j) acc[i][j] = 0.f;
    #pragma unroll
    for (int k = 0; k < HID; ++k) {
        float a[4];
        #pragma unroll
        for (int ii = 0; ii < 4; ++ii) a[ii] = t1s[ty * 4 + ii][k];
        float4 w = *(const float4*)&Ws[k][tx * 4];
        #pragma unroll
        for (int ii = 0; ii < 4; ++ii) {
            acc[ii][0] += a[ii] * w.x;
            acc[ii][1] += a[ii] * w.y;
            acc[ii][2] += a[ii] * w.z;
            acc[ii][3] += a[ii] * w.w;
        }
    }
    #pragma unroll
    for (int ii = 0; ii < 4; ++ii) {
        float o[4];
        #pragma unroll
        for (int jj = 0; jj < 4; ++jj) o[jj] = acc[ii][jj] + b2s[tx * 4 + jj];
        *(float4*)&h1[(size_t)(row0 + ty * 4 + ii) * HID + tx * 4] = *(float4*)&o[0];
    }
}

// ---------------- K6: hs = h1_i + sum h1_n; t2 = relu(hs@W1b+b1b); z = t2@W2b+b2b ----------------
__global__ __launch_bounds__(256) void t2z_kernel(const float* __restrict__ h1,
                                                  const int* __restrict__ knn_idx,
                                                  const float* __restrict__ W1,
                                                  const float* __restrict__ bias1,
                                                  const float* __restrict__ W2,
                                                  const float* __restrict__ bias2,
                                                  float* __restrict__ z) {
    int row0 = blockIdx.x * 64;
    int m = row0 >> 10;
    __shared__ int nb[64 * KNN];
    __shared__ float hs[64][65];
    __shared__ float t2s[64][65];
    __shared__ float Ws[64][HID];
    __shared__ float b1s[HID], b2s[HID];
    int tid = threadIdx.x;
    for (int k = tid; k < 64 * KNN; k += 256) nb[k] = knn_idx[(size_t)row0 * KNN + k];
    for (int k = tid; k < 64 * HID; k += 256) Ws[k >> 6][k & 63] = W1[k];
    if (tid < HID) { b1s[tid] = bias1[tid]; b2s[tid] = bias2[tid]; }
    __syncthreads();
    {
        int r = tid >> 2, c0 = (tid & 3) * 16;
        const float* hr = h1 + (size_t)(row0 + r) * HID + c0;
        float4 a[4];
        #pragma unroll
        for (int q = 0; q < 4; ++q) a[q] = *(const float4*)&hr[q * 4];
        const float* hm = h1 + (size_t)(m << 10) * HID;
        #pragma unroll
        for (int t = 0; t < KNN; ++t) {
            const float* hn = hm + (size_t)nb[r * KNN + t] * HID + c0;
            #pragma unroll
            for (int q = 0; q < 4; ++q) {
                float4 v = *(const float4*)&hn[q * 4];
                a[q].x += v.x; a[q].y += v.y; a[q].z += v.z; a[q].w += v.w;
            }
        }
        #pragma unroll
        for (int q = 0; q < 4; ++q) *(float4*)&hs[r][c0 + q * 4] = a[q];
    }
    __syncthreads();
    int ty = tid >> 4, tx = tid & 15;
    float acc[4][4];
    #pragma unroll
    for (int i = 0; i < 4; ++i)
        #pragma unroll
        for (int j = 0; j < 4; ++j) acc[i][j] = 0.f;
    #pragma unroll
    for (int k = 0; k < HID; ++k) {
        float a[4];
        #pragma unroll
        for (int ii = 0; ii < 4; ++ii) a[ii] = hs[ty * 4 + ii][k];
        float4 w = *(const float4*)&Ws[k][tx * 4];
        #pragma unroll
        for (int ii = 0; ii < 4; ++ii) {
            acc[ii][0] += a[ii] * w.x;
            acc[ii][1] += a[ii] * w.y;
            acc[ii][2] += a[ii] * w.z;
            acc[ii][3] += a[ii] * w.w;
        }
    }
    #pragma unroll
    for (int ii = 0; ii < 4; ++ii)
        #pragma unroll
        for (int jj = 0; jj < 4; ++jj)
            t2s[ty * 4 + ii][tx * 4 + jj] = fmaxf(acc[ii][jj] + b1s[tx * 4 + jj], 0.f);
    __syncthreads();
    for (int k = tid; k < 64 * HID; k += 256) Ws[k >> 6][k & 63] = W2[k];
    __syncthreads();
    #pragma unroll
    for (int i = 0; i < 4; ++i)
        #pragma unroll
        for (int j = 0; j < 4; ++j) acc[i][j] = 0.f;
    #pragma unroll
    for (int k = 0; k < HID; ++k) {
        float a[4];
        #pragma unroll
        for (int ii = 0; ii < 4; ++ii) a[ii] = t2s[ty * 4 + ii][k];
        float4 w = *(const float4*)&Ws[k][tx * 4];
        #pragma unroll
        for (int ii = 0; ii < 4; ++ii) {
            acc[ii][0] += a[ii] * w.x;
            acc[ii][1] += a[ii] * w.y;
            acc[ii][2] += a[ii] * w.z;
            acc[ii][3] += a[ii] * w.w;
        }
    }
    #pragma unroll
    for (int ii = 0; ii < 4; ++ii) {
        float o[4];
        #pragma unroll
        for (int jj = 0; jj < 4; ++jj) o[jj] = acc[ii][jj] + b2s[tx * 4 + jj];
        *(float4*)&z[(size_t)(row0 + ty * 4 + ii) * HID + tx * 4] = *(float4*)&o[0];
    }
}

// ---------------- K7: sim = z1 @ z2^T (64x64 tiles, K=64) ----------------
__global__ __launch_bounds__(256) void sim_kernel(const float* __restrict__ z,
                                                  float* __restrict__ logits) {
    int bid = blockIdx.x;
    int b = bid >> 8;
    int tile = bid & 255;
    int ti = (tile >> 4) << 6;
    int tj = (tile & 15) << 6;
    const float* z1 = z + (size_t)b * NPTS * HID;
    const float* z2 = z + (size_t)(BATCH + b) * NPTS * HID;
    __shared__ float Z1[64][68];
    __shared__ float Z2[64][68];
    int tid = threadIdx.x;
    #pragma unroll
    for (int i = 0; i < 4; ++i) {
        int l = tid + i * 256;
        int r = l >> 4, c = (l & 15) * 4;
        *(float4*)&Z1[r][c] = *(const float4*)&z1[(size_t)(ti + r) * HID + c];
        *(float4*)&Z2[r][c] = *(const float4*)&z2[(size_t)(tj + r) * HID + c];
    }
    __syncthreads();
    int ty = tid >> 4, tx = tid & 15;
    float acc[4][4];
    #pragma unroll
    for (int i = 0; i < 4; ++i)
        #pragma unroll
        for (int j = 0; j < 4; ++j) acc[i][j] = 0.f;
    #pragma unroll
    for (int h = 0; h < HID; ++h) {
        float a[4], bb[4];
        #pragma unroll
        for (int ii = 0; ii < 4; ++ii) { a[ii] = Z1[ty * 4 + ii][h]; bb[ii] = Z2[tx * 4 + ii][h]; }
        #pragma unroll
        for (int ii = 0; ii < 4; ++ii)
            #pragma unroll
            for (int jj = 0; jj < 4; ++jj)
                acc[ii][jj] += a[ii] * bb[jj];
    }
    #pragma unroll
    for (int ii = 0; ii < 4; ++ii) {
        float* dst = logits + ((size_t)b * NPTS + ti + ty * 4 + ii) * NPTS + tj + tx * 4;
        *(float4*)&dst[0] = *(float4*)&acc[ii][0];
    }
}

// ---------------- K8: row softmax ----------------
__global__ __launch_bounds__(256) void softmax_kernel(const float* __restrict__ logits,
                                                      float* __restrict__ out) {
    int row = blockIdx.x;                         // 0..8191
    const float* L = logits + (size_t)row * NPTS;
    __shared__ float buf[NPTS];
    __shared__ float red[8];
    int tid = threadIdx.x;
    int wave = tid >> 6, lane = tid & 63;
    float mx = -3e38f;
    #pragma unroll
    for (int s = 0; s < 4; ++s) {
        float v = L[tid + s * 256];
        buf[tid + s * 256] = v;
        mx = fmaxf(mx, v);
    }
    #pragma unroll
    for (int off = 32; off > 0; off >>= 1) mx = fmaxf(mx, __shfl_down(mx, off));
    if (lane == 0) red[wave] = mx;
    __syncthreads();
    mx = fmaxf(fmaxf(red[0], red[1]), fmaxf(red[2], red[3]));
    float sum = 0.f;
    #pragma unroll
    for (int s = 0; s < 4; ++s) {
        float e = expf(buf[tid + s * 256] - mx);
        buf[tid + s * 256] = e;
        sum += e;
    }
    #pragma unroll
    for (int off = 32; off > 0; off >>= 1) sum += __shfl_down(sum, off);
    if (lane == 0) red[4 + wave] = sum;
    __syncthreads();
    float inv = 1.f / (red[4] + red[5] + red[6] + red[7]);
    #pragma unroll
    for (int s = 0; s < 4; ++s)
        out[(size_t)row * NPTS + tid + s * 256] = buf[tid + s * 256] * inv;
}

extern "C" void kernel_launch(void* const* d_in, const int* in_sizes, int n_in,
                              void* d_out, int out_size, void* d_ws, size_t ws_size,
                              hipStream_t stream) {
    const float* f1  = (const float*)d_in[0];
    const float* f2  = (const float*)d_in[1];
    const float* W1a = (const float*)d_in[2];
    const float* b1a = (const float*)d_in[3];
    const float* W2a = (const float*)d_in[4];
    const float* b2a = (const float*)d_in[5];
    const float* W1b = (const float*)d_in[6];
    const float* b1b = (const float*)d_in[7];
    const float* W2b = (const float*)d_in[8];
    const float* b2b = (const float*)d_in[9];
    float* out = (float*)d_out;

    // workspace: H packed (100.7MB) | dist (67.1MB, reused as sim logits) | sq | kidx | y | h1 | z
    char* ws = (char*)d_ws;
    unsigned short* H = (unsigned short*)ws;
    float* dist = (float*)(ws + (size_t)NMAT * NPTS * KPACK * sizeof(unsigned short));
    float* sq   = dist + (size_t)NMAT * NPTS * NPTS;
    int*   kidx = (int*)(sq + NMAT * NPTS);
    float* ybuf = (float*)(kidx + NMAT * NPTS * KNN);
    float* h1b  = ybuf + (size_t)NMAT * NPTS * HID;
    float* zb   = h1b + (size_t)NMAT * NPTS * HID;

    split_ymlp_kernel<<<NMAT * NPTS / 64, 512, 0, stream>>>(f1, f2, W1a, H, sq, ybuf);
    gram_mfma_kernel<<<NMAT * 36, 512, 0, stream>>>(H, sq, dist);
    topk_kernel<<<NMAT * NPTS / 4, 256, 0, stream>>>(dist, kidx);
    t1h1_kernel<<<NMAT * NPTS / 64, 256, 0, stream>>>(ybuf, kidx, W2a, b1a, b2a, h1b);
    t2z_kernel<<<NMAT * NPTS / 64, 256, 0, stream>>>(h1b, kidx, W1b, b1b, W2b, b2b, zb);
    sim_kernel<<<BATCH * 256, 256, 0, stream>>>(zb, dist);                      // dist := logits
    softmax_kernel<<<BATCH * NPTS, 256, 0, stream>>>(dist, out);
}

// Round 12
// 483.317 us; speedup vs baseline: 1.5980x; 1.0300x over previous
//
#include <hip/hip_runtime.h>
#include <hip/hip_bf16.h>
#include <math.h>

#define BATCH 8
#define NPTS  1024
#define DIM   1024
#define HID   64
#define KNN   20
#define NMAT  16
#define KPACK 3072   // 3 bf16 segments stored contiguously per row: k = seg*1024 + d

typedef __attribute__((ext_vector_type(8))) short short8;
typedef __attribute__((ext_vector_type(4))) float floatx4;

__device__ __forceinline__ const float* mat_base(const float* f1, const float* f2, int m) {
    return (m < BATCH) ? (f1 + (size_t)m * NPTS * DIM)
                       : (f2 + (size_t)(m - BATCH) * NPTS * DIM);
}

__device__ __forceinline__ unsigned short f2bf_bits(float v) {
    __hip_bfloat16 h = __float2bfloat16(v);   // RNE
    return *(unsigned short*)&h;
}
__device__ __forceinline__ float bfbits2f(unsigned short b) {
    union { unsigned u; float f; } c; c.u = ((unsigned)b) << 16; return c.f;
}

// ---------------- K1: FUSED 3-way bf16 split + squared norms + y = f @ W1a ----------------
// R10 version (proven): 512 threads, 32-k chunks, 8 waves/CU.
__global__ __launch_bounds__(512) void split_ymlp_kernel(const float* __restrict__ f1,
                                                         const float* __restrict__ f2,
                                                         const float* __restrict__ W,
                                                         unsigned short* __restrict__ H,
                                                         float* __restrict__ sq,
                                                         float* __restrict__ y) {
    int row0 = blockIdx.x * 64;                 // 64-row blocks never straddle matrices
    int m = row0 >> 10;
    const float* A = mat_base(f1, f2, m) + (size_t)(row0 & (NPTS - 1)) * DIM;
    unsigned short* Hb = H + (size_t)row0 * KPACK;
    __shared__ float As[64][36];                // 32 k-cols + 4 pad
    __shared__ float Ws[32][68];                // 32 k-rows x 64 cols + 4 pad
    int tid = threadIdx.x;                      // 0..511
    int r = tid >> 3, cq = (tid & 7) * 4;       // load map: row r (8 thr/row), cols cq..cq+3
    int ty = tid >> 4, tx = tid & 15;           // GEMM map: rows ty*2..+1, cols tx*4..+3
    float acc[2][4];
    #pragma unroll
    for (int i = 0; i < 2; ++i)
        #pragma unroll
        for (int j = 0; j < 4; ++j) acc[i][j] = 0.f;
    float sqp = 0.f;
    unsigned short* Hr = Hb + (size_t)r * KPACK + cq;

    for (int kk = 0; kk < DIM; kk += 32) {
        float4 a = *(const float4*)&A[(size_t)r * DIM + kk + cq];
        // ---- split (bitwise-identical elementwise chain) ----
        {
            float vv[4] = {a.x, a.y, a.z, a.w};
            unsigned short h1[4], h2[4], h3[4];
            #pragma unroll
            for (int c = 0; c < 4; ++c) {
                unsigned short b1 = f2bf_bits(vv[c]);
                float r1 = vv[c] - bfbits2f(b1);
                unsigned short b2 = f2bf_bits(r1);
                float r2 = r1 - bfbits2f(b2);
                unsigned short b3 = f2bf_bits(r2);
                h1[c] = b1; h2[c] = b2; h3[c] = b3;
            }
            *(ushort4*)&Hr[kk]        = *(ushort4*)&h1[0];
            *(ushort4*)&Hr[1024 + kk] = *(ushort4*)&h2[0];
            *(ushort4*)&Hr[2048 + kk] = *(ushort4*)&h3[0];
            sqp += a.x * a.x + a.y * a.y + a.z * a.z + a.w * a.w;
        }
        // ---- GEMM staging ----
        *(float4*)&As[r][cq] = a;
        {
            int d = tid >> 4, hh = (tid & 15) * 4;   // 32 k-rows x 16 col-groups
            *(float4*)&Ws[d][hh] = *(const float4*)&W[(size_t)(kk + d) * HID + hh];
        }
        __syncthreads();
        #pragma unroll
        for (int k = 0; k < 32; ++k) {
            float av[2];
            #pragma unroll
            for (int ii = 0; ii < 2; ++ii) av[ii] = As[ty * 2 + ii][k];
            float4 w = *(const float4*)&Ws[k][tx * 4];
            #pragma unroll
            for (int ii = 0; ii < 2; ++ii) {
                acc[ii][0] += av[ii] * w.x;
                acc[ii][1] += av[ii] * w.y;
                acc[ii][2] += av[ii] * w.z;
                acc[ii][3] += av[ii] * w.w;
            }
        }
        __syncthreads();
    }
    sqp += __shfl_down(sqp, 4);
    sqp += __shfl_down(sqp, 2);
    sqp += __shfl_down(sqp, 1);
    if ((tid & 7) == 0) sq[row0 + r] = sqp;
    #pragma unroll
    for (int ii = 0; ii < 2; ++ii)
        *(float4*)&y[(size_t)(row0 + ty * 2 + ii) * HID + tx * 4] = *(float4*)&acc[ii][0];
}

// ---------------- K2: Gram -> squared distances via bf16 MFMA ----------------
// R11 version (best known: 185us, 28.8% occ): 512 threads / 8 waves, 16 rows x 128 cols
// per wave, triple-buffered B (3x24KB), vmcnt(12) counted pipeline, R9 prologue drain.
// SHELVED: R3 (depth), R10/R11 (occupancy), R4/R9 (retile) all pin ~185us -> the 905MB
// staged stream at ~5 TB/s is the ceiling for this geometry. Do not touch.
#define GRAM_STEP(CURAF, NXTAF, CBUF, NBUF, KN, ISSUE, WAITOP)                             \
  {                                                                                        \
    if (ISSUE) {                                                                           \
      _Pragma("unroll")                                                                    \
      for (int s = 0; s < 3; ++s)                                                          \
        NXTAF[s] = *(const short8*)&Hm[(size_t)(ti + (w << 4) + r16) * KPACK               \
                                       + (size_t)(s << 10) + (KN) + (kc << 3)];            \
      _Pragma("unroll")                                                                    \
      for (int c = 0; c < 3; ++c) {                                                        \
        int ca = w * 3 + c; int seg = ca >> 3; int rb = ca & 7;                            \
        const unsigned short* gb = Hm + (size_t)(tj + rb * 16 + r16) * KPACK               \
                                      + (size_t)(seg << 10) + (KN) + (kc << 3);            \
        __builtin_amdgcn_global_load_lds(                                                  \
            (const __attribute__((address_space(1))) void*)gb,                             \
            (__attribute__((address_space(3))) void*)&Bsl[NBUF][ca * 512], 16, 0, 0);      \
      }                                                                                    \
    }                                                                                      \
    asm volatile(WAITOP ::: "memory");                                                     \
    __builtin_amdgcn_s_barrier();                                                          \
    asm volatile("" ::: "memory");                                                         \
    __builtin_amdgcn_s_setprio(1);                                                         \
    _Pragma("unroll")                                                                      \
    for (int sb = 0; sb < 3; ++sb) {                                                       \
      short8 bf[8];                                                                        \
      _Pragma("unroll")                                                                    \
      for (int b = 0; b < 8; ++b)                                                          \
        bf[b] = *(const short8*)&Bsl[CBUF][(sb * 8 + b) * 512 + lane * 8];                 \
      _Pragma("unroll")                                                                    \
      for (int sa = 0; sa < 3; ++sa) {                                                     \
        if (sa + sb > 2) continue;                                                         \
        _Pragma("unroll")                                                                  \
        for (int b = 0; b < 8; ++b)                                                        \
          acc[b] = __builtin_amdgcn_mfma_f32_16x16x32_bf16(CURAF[sa], bf[b],               \
                                                           acc[b], 0, 0, 0);               \
      }                                                                                    \
    }                                                                                      \
    __builtin_amdgcn_s_setprio(0);                                                         \
    asm volatile("" ::: "memory");                                                         \
    __builtin_amdgcn_s_barrier();                                                          \
  }

__global__ __launch_bounds__(512, 4) void gram_mfma_kernel(const unsigned short* __restrict__ H,
                                                           const float* __restrict__ sq,
                                                           float* __restrict__ dist) {
    int bid = blockIdx.x;
    int xcd = bid & 7;
    int g = bid >> 3;                 // 0..71
    int m = xcd + 8 * (g & 1);        // interleave this XCD's two matrices
    int t = g >> 1;                   // 0..35
    int bi = 0;
    { int a = t; while (a >= 8 - bi) { a -= 8 - bi; ++bi; } t = a; }
    int bj = bi + t;
    int ti = bi << 7, tj = bj << 7;

    const unsigned short* Hm = H + (size_t)m * NPTS * KPACK;

    // B chunks: ca = seg*8 + colblk ; each chunk: [lane(64)][8 shorts] = 1KB (16 cols x 32 k)
    __shared__ __align__(16) unsigned short Bsl[3][24 * 512];   // 3 x 24 KB triple buffer

    int tid = threadIdx.x;
    int w = tid >> 6, lane = tid & 63;   // 8 waves; wave owns rows ti + w*16 .. +15
    int r16 = lane & 15, kc = lane >> 4;

    floatx4 acc[8];
    #pragma unroll
    for (int b = 0; b < 8; ++b) acc[b] = (floatx4)0.f;

    // A fragment triple buffers: wave-private rows (3 segs x 1 rowblock each)
    short8 afA[3], afB[3], afC[3];

    // ---- prologue (grouped: afA | B0-DMA | afB | B1-DMA, then full drain) ----
    #pragma unroll
    for (int s = 0; s < 3; ++s)
        afA[s] = *(const short8*)&Hm[(size_t)(ti + (w << 4) + r16) * KPACK
                                     + (size_t)(s << 10) + (kc << 3)];
    asm volatile("" ::: "memory");
    #pragma unroll
    for (int c = 0; c < 3; ++c) {
        int ca = w * 3 + c; int seg = ca >> 3; int rb = ca & 7;
        const unsigned short* gb = Hm + (size_t)(tj + rb * 16 + r16) * KPACK
                                      + (size_t)(seg << 10) + (kc << 3);
        __builtin_amdgcn_global_load_lds(
            (const __attribute__((address_space(1))) void*)gb,
            (__attribute__((address_space(3))) void*)&Bsl[0][ca * 512], 16, 0, 0);
    }
    asm volatile("" ::: "memory");
    #pragma unroll
    for (int s = 0; s < 3; ++s)
        afB[s] = *(const short8*)&Hm[(size_t)(ti + (w << 4) + r16) * KPACK
                                     + (size_t)(s << 10) + 32 + (kc << 3)];
    asm volatile("" ::: "memory");
    #pragma unroll
    for (int c = 0; c < 3; ++c) {
        int ca = w * 3 + c; int seg = ca >> 3; int rb = ca & 7;
        const unsigned short* gb = Hm + (size_t)(tj + rb * 16 + r16) * KPACK
                                      + (size_t)(seg << 10) + 32 + (kc << 3);
        __builtin_amdgcn_global_load_lds(
            (const __attribute__((address_space(1))) void*)gb,
            (__attribute__((address_space(3))) void*)&Bsl[1][ca * 512], 16, 0, 0);
    }
    // Full drain: slices 0/1 complete before the loop; steps 0/1's vmcnt(12) are
    // no-ops (6/12 outstanding); steady state from step 2 retires exactly one slice.
    asm volatile("s_waitcnt vmcnt(0)" ::: "memory");

    // slices 0..29: compute t, issue t+2, wait vmcnt(12) (t+1,t+2 in flight: 6+6)
    #pragma unroll 1
    for (int t2 = 0; t2 < 30; t2 += 3) {
        GRAM_STEP(afA, afC, 0, 2, (t2 + 2) * 32, 1, "s_waitcnt vmcnt(12)");
        GRAM_STEP(afB, afA, 1, 0, (t2 + 3) * 32, 1, "s_waitcnt vmcnt(12)");
        GRAM_STEP(afC, afB, 2, 1, (t2 + 4) * 32, 1, "s_waitcnt vmcnt(12)");
    }
    // epilogue: slice 30 (slice 31 still in flight), then slice 31
    GRAM_STEP(afA, afC, 0, 2, 0, 0, "s_waitcnt vmcnt(6)");
    GRAM_STEP(afB, afC, 1, 2, 0, 0, "s_waitcnt vmcnt(0)");

    const float* sqm = sq + m * NPTS;
    {
        int i0 = ti + (w << 4) + (lane >> 4) * 4;
        #pragma unroll
        for (int b = 0; b < 8; ++b) {
            int j = tj + b * 16 + (lane & 15);
            float sqj = sqm[j];
            #pragma unroll
            for (int r = 0; r < 4; ++r) {
                int i = i0 + r;
                float v = sqm[i] + sqj - 2.f * acc[b][r];
                if (i == j) v += 1e10f;
                dist[((size_t)m * NPTS + i) * NPTS + j] = v;
                if (bi != bj) dist[((size_t)m * NPTS + j) * NPTS + i] = v;
            }
        }
    }
}

// ---------------- K3: top-k (k=20 smallest), one wave per row, all-register ----------------
__global__ __launch_bounds__(256) void topk_kernel(const float* __restrict__ dist,
                                                   int* __restrict__ knn_idx) {
    int tid = threadIdx.x;
    int wave = tid >> 6, lane = tid & 63;
    int row = blockIdx.x * 4 + wave;
    const float* d = dist + (size_t)row * NPTS;
    float v[16];
    #pragma unroll
    for (int s = 0; s < 16; ++s) v[s] = d[s * 64 + lane];
    int myj = 0;
    for (int sel = 0; sel < KNN; ++sel) {
        float bv = v[0]; int bs = 0;
        #pragma unroll
        for (int s = 1; s < 16; ++s)
            if (v[s] < bv) { bv = v[s]; bs = s; }   // ascending s: lowest j locally on ties
        int bj = bs * 64 + lane;
        #pragma unroll
        for (int off = 1; off < 64; off <<= 1) {
            float ov = __shfl_xor(bv, off);
            int   oj = __shfl_xor(bj, off);
            if (ov < bv || (ov == bv && oj < bj)) { bv = ov; bj = oj; }
        }
        if ((bj & 63) == lane) v[bj >> 6] = 3e38f;  // owner clears
        if (lane == sel) myj = bj;
    }
    if (lane < KNN) knn_idx[(size_t)row * KNN + lane] = myj;
}

// ---------------- K5: t1 = relu(y_i + sum y_n + b1a); h1 = t1 @ W2a + b2a ----------------
// R12: 512-thread restructure (R10's proven occupancy treatment). Old: 256 threads,
// 256 blocks = 1 block/CU = 4 waves/CU, gather latency exposed. New: 512 threads
// = 8 waves/CU. Gather: 8 thr/row x 8 cols (2 float4s); GEMM: 32 row-pairs x 16
// col-quads, acc[2][4]. Per-element chains unchanged (gather ascending t; GEMM
// ascending k) -> h1 bitwise identical.
__global__ __launch_bounds__(512) void t1h1_kernel(const float* __restrict__ y,
                                                   const int* __restrict__ knn_idx,
                                                   const float* __restrict__ W,
                                                   const float* __restrict__ bias1,
                                                   const float* __restrict__ bias2,
                                                   float* __restrict__ h1) {
    int row0 = blockIdx.x * 64;
    int m = row0 >> 10;
    __shared__ int nb[64 * KNN];
    __shared__ float t1s[64][65];
    __shared__ float Ws[64][HID];
    __shared__ float b1s[HID], b2s[HID];
    int tid = threadIdx.x;                       // 0..511
    for (int k = tid; k < 64 * KNN; k += 512) nb[k] = knn_idx[(size_t)row0 * KNN + k];
    for (int k = tid; k < 64 * HID; k += 512) Ws[k >> 6][k & 63] = W[k];
    if (tid < HID) { b1s[tid] = bias1[tid]; b2s[tid] = bias2[tid]; }
    __syncthreads();
    {
        int r = tid >> 3, c0 = (tid & 7) * 8;    // 8 threads/row, 8 cols each
        const float* yr = y + (size_t)(row0 + r) * HID + c0;
        float4 a[2];
        #pragma unroll
        for (int q = 0; q < 2; ++q) a[q] = *(const float4*)&yr[q * 4];
        const float* ym = y + (size_t)(m << 10) * HID;
        #pragma unroll
        for (int t = 0; t < KNN; ++t) {
            const float* yn = ym + (size_t)nb[r * KNN + t] * HID + c0;
            #pragma unroll
            for (int q = 0; q < 2; ++q) {
                float4 v = *(const float4*)&yn[q * 4];
                a[q].x += v.x; a[q].y += v.y; a[q].z += v.z; a[q].w += v.w;
            }
        }
        #pragma unroll
        for (int q = 0; q < 2; ++q) {
            int c = c0 + q * 4;
            t1s[r][c + 0] = fmaxf(a[q].x + b1s[c + 0], 0.f);
            t1s[r][c + 1] = fmaxf(a[q].y + b1s[c + 1], 0.f);
            t1s[r][c + 2] = fmaxf(a[q].z + b1s[c + 2], 0.f);
            t1s[r][c + 3] = fmaxf(a[q].w + b1s[c + 3], 0.f);
        }
    }
    __syncthreads();
    int ty = tid >> 4, tx = tid & 15;            // rows ty*2..+1, cols tx*4..+3
    float acc[2][4];
    #pragma unroll
    for (int i = 0; i < 2; ++i)
        #pragma unroll
        for (int j = 0; j < 4; ++j) acc[i][j] = 0.f;
    #pragma unroll
    for (int k = 0; k < HID; ++k) {
        float a[2];
        #pragma unroll
        for (int ii = 0; ii < 2; ++ii) a[ii] = t1s[ty * 2 + ii][k];
        float4 w = *(const float4*)&Ws[k][tx * 4];
        #pragma unroll
        for (int ii = 0; ii < 2; ++ii) {
            acc[ii][0] += a[ii] * w.x;
            acc[ii][1] += a[ii] * w.y;
            acc[ii][2] += a[ii] * w.z;
            acc[ii][3] += a[ii] * w.w;
        }
    }
    #pragma unroll
    for (int ii = 0; ii < 2; ++ii) {
        float o[4];
        #pragma unroll
        for (int jj = 0; jj < 4; ++jj) o[jj] = acc[ii][jj] + b2s[tx * 4 + jj];
        *(float4*)&h1[(size_t)(row0 + ty * 2 + ii) * HID + tx * 4] = *(float4*)&o[0];
    }
}

// ---------------- K6: hs = h1_i + sum h1_n; t2 = relu(hs@W1b+b1b); z = t2@W2b+b2b ----------------
// R12: same 512-thread treatment as t1h1. Chains unchanged -> z bitwise identical.
__global__ __launch_bounds__(512) void t2z_kernel(const float* __restrict__ h1,
                                                  const int* __restrict__ knn_idx,
                                                  const float* __restrict__ W1,
                                                  const float* __restrict__ bias1,
                                                  const float* __restrict__ W2,
                                                  const float* __restrict__ bias2,
                                                  float* __restrict__ z) {
    int row0 = blockIdx.x * 64;
    int m = row0 >> 10;
    __shared__ int nb[64 * KNN];
    __shared__ float hs[64][65];
    __shared__ float t2s[64][65];
    __shared__ float Ws[64][HID];
    __shared__ float b1s[HID], b2s[HID];
    int tid = threadIdx.x;                       // 0..511
    for (int k = tid; k < 64 * KNN; k += 512) nb[k] = knn_idx[(size_t)row0 * KNN + k];
    for (int k = tid; k < 64 * HID; k += 512) Ws[k >> 6][k & 63] = W1[k];
    if (tid < HID) { b1s[tid] = bias1[tid]; b2s[tid] = bias2[tid]; }
    __syncthreads();
    {
        int r = tid >> 3, c0 = (tid & 7) * 8;
        const float* hr = h1 + (size_t)(row0 + r) * HID + c0;
        float4 a[2];
        #pragma unroll
        for (int q = 0; q < 2; ++q) a[q] = *(const float4*)&hr[q * 4];
        const float* hm = h1 + (size_t)(m << 10) * HID;
        #pragma unroll
        for (int t = 0; t < KNN; ++t) {
            const float* hn = hm + (size_t)nb[r * KNN + t] * HID + c0;
            #pragma unroll
            for (int q = 0; q < 2; ++q) {
                float4 v = *(const float4*)&hn[q * 4];
                a[q].x += v.x; a[q].y += v.y; a[q].z += v.z; a[q].w += v.w;
            }
        }
        #pragma unroll
        for (int q = 0; q < 2; ++q) *(float4*)&hs[r][c0 + q * 4] = a[q];
    }
    __syncthreads();
    int ty = tid >> 4, tx = tid & 15;
    float acc[2][4];
    #pragma unroll
    for (int i = 0; i < 2; ++i)
        #pragma unroll
        for (int j = 0; j < 4; ++j) acc[i][j] = 0.f;
    #pragma unroll
    for (int k = 0; k < HID; ++k) {
        float a[2];
        #pragma unroll
        for (int ii = 0; ii < 2; ++ii) a[ii] = hs[ty * 2 + ii][k];
        float4 w = *(const float4*)&Ws[k][tx * 4];
        #pragma unroll
        for (int ii = 0; ii < 2; ++ii) {
            acc[ii][0] += a[ii] * w.x;
            acc[ii][1] += a[ii] * w.y;
            acc[ii][2] += a[ii] * w.z;
            acc[ii][3] += a[ii] * w.w;
        }
    }
    #pragma unroll
    for (int ii = 0; ii < 2; ++ii)
        #pragma unroll
        for (int jj = 0; jj < 4; ++jj)
            t2s[ty * 2 + ii][tx * 4 + jj] = fmaxf(acc[ii][jj] + b1s[tx * 4 + jj], 0.f);
    __syncthreads();
    for (int k = tid; k < 64 * HID; k += 512) Ws[k >> 6][k & 63] = W2[k];
    __syncthreads();
    #pragma unroll
    for (int i = 0; i < 2; ++i)
        #pragma unroll
        for (int j = 0; j < 4; ++j) acc[i][j] = 0.f;
    #pragma unroll
    for (int k = 0; k < HID; ++k) {
        float a[2];
        #pragma unroll
        for (int ii = 0; ii < 2; ++ii) a[ii] = t2s[ty * 2 + ii][k];
        float4 w = *(const float4*)&Ws[k][tx * 4];
        #pragma unroll
        for (int ii = 0; ii < 2; ++ii) {
            acc[ii][0] += a[ii] * w.x;
            acc[ii][1] += a[ii] * w.y;
            acc[ii][2] += a[ii] * w.z;
            acc[ii][3] += a[ii] * w.w;
        }
    }
    #pragma unroll
    for (int ii = 0; ii < 2; ++ii) {
        float o[4];
        #pragma unroll
        for (int jj = 0; jj < 4; ++jj) o[jj] = acc[ii][jj] + b2s[tx * 4 + jj];
        *(float4*)&z[(size_t)(row0 + ty * 2 + ii) * HID + tx * 4] = *(float4*)&o[0];
    }
}

// ---------------- K7: sim = z1 @ z2^T (64x64 tiles, K=64) ----------------
__global__ __launch_bounds__(256) void sim_kernel(const float* __restrict__ z,
                                                  float* __restrict__ logits) {
    int bid = blockIdx.x;
    int b = bid >> 8;
    int tile = bid & 255;
    int ti = (tile >> 4) << 6;
    int tj = (tile & 15) << 6;
    const float* z1 = z + (size_t)b * NPTS * HID;
    const float* z2 = z + (size_t)(BATCH + b) * NPTS * HID;
    __shared__ float Z1[64][68];
    __shared__ float Z2[64][68];
    int tid = threadIdx.x;
    #pragma unroll
    for (int i = 0; i < 4; ++i) {
        int l = tid + i * 256;
        int r = l >> 4, c = (l & 15) * 4;
        *(float4*)&Z1[r][c] = *(const float4*)&z1[(size_t)(ti + r) * HID + c];
        *(float4*)&Z2[r][c] = *(const float4*)&z2[(size_t)(tj + r) * HID + c];
    }
    __syncthreads();
    int ty = tid >> 4, tx = tid & 15;
    float acc[4][4];
    #pragma unroll
    for (int i = 0; i < 4; ++i)
        #pragma unroll
        for (int j = 0; j < 4; ++j) acc[i][j] = 0.f;
    #pragma unroll
    for (int h = 0; h < HID; ++h) {
        float a[4], bb[4];
        #pragma unroll
        for (int ii = 0; ii < 4; ++ii) { a[ii] = Z1[ty * 4 + ii][h]; bb[ii] = Z2[tx * 4 + ii][h]; }
        #pragma unroll
        for (int ii = 0; ii < 4; ++ii)
            #pragma unroll
            for (int jj = 0; jj < 4; ++jj)
                acc[ii][jj] += a[ii] * bb[jj];
    }
    #pragma unroll
    for (int ii = 0; ii < 4; ++ii) {
        float* dst = logits + ((size_t)b * NPTS + ti + ty * 4 + ii) * NPTS + tj + tx * 4;
        *(float4*)&dst[0] = *(float4*)&acc[ii][0];
    }
}

// ---------------- K8: row softmax ----------------
__global__ __launch_bounds__(256) void softmax_kernel(const float* __restrict__ logits,
                                                      float* __restrict__ out) {
    int row = blockIdx.x;                         // 0..8191
    const float* L = logits + (size_t)row * NPTS;
    __shared__ float buf[NPTS];
    __shared__ float red[8];
    int tid = threadIdx.x;
    int wave = tid >> 6, lane = tid & 63;
    float mx = -3e38f;
    #pragma unroll
    for (int s = 0; s < 4; ++s) {
        float v = L[tid + s * 256];
        buf[tid + s * 256] = v;
        mx = fmaxf(mx, v);
    }
    #pragma unroll
    for (int off = 32; off > 0; off >>= 1) mx = fmaxf(mx, __shfl_down(mx, off));
    if (lane == 0) red[wave] = mx;
    __syncthreads();
    mx = fmaxf(fmaxf(red[0], red[1]), fmaxf(red[2], red[3]));
    float sum = 0.f;
    #pragma unroll
    for (int s = 0; s < 4; ++s) {
        float e = expf(buf[tid + s * 256] - mx);
        buf[tid + s * 256] = e;
        sum += e;
    }
    #pragma unroll
    for (int off = 32; off > 0; off >>= 1) sum += __shfl_down(sum, off);
    if (lane == 0) red[4 + wave] = sum;
    __syncthreads();
    float inv = 1.f / (red[4] + red[5] + red[6] + red[7]);
    #pragma unroll
    for (int s = 0; s < 4; ++s)
        out[(size_t)row * NPTS + tid + s * 256] = buf[tid + s * 256] * inv;
}

extern "C" void kernel_launch(void* const* d_in, const int* in_sizes, int n_in,
                              void* d_out, int out_size, void* d_ws, size_t ws_size,
                              hipStream_t stream) {
    const float* f1  = (const float*)d_in[0];
    const float* f2  = (const float*)d_in[1];
    const float* W1a = (const float*)d_in[2];
    const float* b1a = (const float*)d_in[3];
    const float* W2a = (const float*)d_in[4];
    const float* b2a = (const float*)d_in[5];
    const float* W1b = (const float*)d_in[6];
    const float* b1b = (const float*)d_in[7];
    const float* W2b = (const float*)d_in[8];
    const float* b2b = (const float*)d_in[9];
    float* out = (float*)d_out;

    // workspace: H packed (100.7MB) | dist (67.1MB, reused as sim logits) | sq | kidx | y | h1 | z
    char* ws = (char*)d_ws;
    unsigned short* H = (unsigned short*)ws;
    float* dist = (float*)(ws + (size_t)NMAT * NPTS * KPACK * sizeof(unsigned short));
    float* sq   = dist + (size_t)NMAT * NPTS * NPTS;
    int*   kidx = (int*)(sq + NMAT * NPTS);
    float* ybuf = (float*)(kidx + NMAT * NPTS * KNN);
    float* h1b  = ybuf + (size_t)NMAT * NPTS * HID;
    float* zb   = h1b + (size_t)NMAT * NPTS * HID;

    split_ymlp_kernel<<<NMAT * NPTS / 64, 512, 0, stream>>>(f1, f2, W1a, H, sq, ybuf);
    gram_mfma_kernel<<<NMAT * 36, 512, 0, stream>>>(H, sq, dist);
    topk_kernel<<<NMAT * NPTS / 4, 256, 0, stream>>>(dist, kidx);
    t1h1_kernel<<<NMAT * NPTS / 64, 512, 0, stream>>>(ybuf, kidx, W2a, b1a, b2a, h1b);
    t2z_kernel<<<NMAT * NPTS / 64, 512, 0, stream>>>(h1b, kidx, W1b, b1b, W2b, b2b, zb);
    sim_kernel<<<BATCH * 256, 256, 0, stream>>>(zb, dist);                      // dist := logits
    softmax_kernel<<<BATCH * NPTS, 256, 0, stream>>>(dist, out);
}